// Round 6
// baseline (1842.425 us; speedup 1.0000x reference)
//
#include <hip/hip_runtime.h>

typedef unsigned short u16;
typedef unsigned int u32;
typedef __bf16 bf16x8 __attribute__((ext_vector_type(8)));
typedef float f32x4 __attribute__((ext_vector_type(4)));

#define N_NODES 32768
#define E_EDGES 262144
#define DP 320          // padded feature dim (300 -> 320)
#define KCAT 960        // padded concat K (900 -> 960)
#define BH_U16 52480    // one 160-col half of padded B: 160*328 u16 (~102.5 KB)

__device__ __forceinline__ float b2f(u16 u) {
    union { u32 u; float f; } x; x.u = ((u32)u) << 16; return x.f;
}
__device__ __forceinline__ u16 f2b(float f) {
    union { float f; u32 u; } x; x.f = f;
    u32 r = x.u + 0x7FFF + ((x.u >> 16) & 1);
    return (u16)(r >> 16);
}
__device__ __forceinline__ u32 bsub2(u32 a, u32 b) {
    float lo = b2f((u16)(a & 0xFFFF)) - b2f((u16)(b & 0xFFFF));
    float hi = b2f((u16)(a >> 16))    - b2f((u16)(b >> 16));
    return (u32)f2b(lo) | ((u32)f2b(hi) << 16);
}

#define GLOAD16(g, l) \
    __builtin_amdgcn_global_load_lds((const __attribute__((address_space(1))) u32*)(g), \
                                     (__attribute__((address_space(3))) u32*)(l), 16, 0, 0)

// ---------------- plain weight transpose (final 960-K projection) ----------------
__global__ void convT_k(const float* __restrict__ src, int R, int C,
                        u16* __restrict__ dst, int KP_, long total) {
    long id = (long)blockIdx.x * blockDim.x + threadIdx.x;
    if (id >= total) return;
    int n = (int)(id / KP_), k = (int)(id % KP_);
    dst[id] = (k < R && n < C) ? f2b(src[(long)k * C + n]) : (u16)0;
}

// ---------------- padded weight build for egemm: dst[h][r][c], c in [0,328) = W[c][h*160+r] ----------------
__global__ void convTswz_k(const float* __restrict__ src, u16* __restrict__ dst) {
    int id = blockIdx.x * 256 + threadIdx.x;
    if (id >= 2 * 160 * 328) return;
    int h = id / BH_U16, rem = id % BH_U16;
    int r = rem / 328, c = rem % 328;
    int n = h * 160 + r;
    dst[id] = (c < 300 && n < 300) ? f2b(src[(long)c * 300 + n]) : (u16)0;
}

// ---------------- activation pad+convert: f32 MxC -> bf16 MxCP (pad 0) ----------------
__global__ void padconv_k(const float* __restrict__ src, int C,
                          u16* __restrict__ dst, int CP, long total) {
    long id = (long)blockIdx.x * blockDim.x + threadIdx.x;
    if (id >= total) return;
    int cw = CP >> 3;
    long row = id / cw;
    int c8 = (int)(id % cw) * 8;
    u32 w[4];
    #pragma unroll
    for (int p = 0; p < 4; ++p) {
        int c0 = c8 + 2 * p, c1 = c0 + 1;
        u16 lo = (c0 < C) ? f2b(src[row * C + c0]) : (u16)0;
        u16 hi = (c1 < C) ? f2b(src[row * C + c1]) : (u16)0;
        w[p] = (u32)lo | ((u32)hi << 16);
    }
    u32* d = (u32*)(dst + row * CP + c8);
    d[0] = w[0]; d[1] = w[1]; d[2] = w[2]; d[3] = w[3];
}

// ================== shared macros for barrier-free egemm kernels ==================
// B frag read from padded LDS [160][328]; A frag per-lane from global; mfma swapped-operand.
#define BLD(buf, kb) { _Pragma("unroll") for (int fc = 0; fc < 5; ++fc) \
    buf[fc] = *(const bf16x8*)&Bs[(wn * 80 + fc * 16 + tl) * 328 + (kb) * 32 + thi * 8]; }
#define MMX(av, bb) { _Pragma("unroll") for (int fr = 0; fr < 4; ++fr) \
    _Pragma("unroll") for (int fc = 0; fc < 5; ++fc) \
        acc[fr][fc] = __builtin_amdgcn_mfma_f32_16x16x32_bf16(bb[fc], av[fr], acc[fr][fc], 0, 0, 0); }

// ---------------- egemm: C(Mx320) = A(Mx320 bf16) @ W (+bias), bf16 out ----------------
// block = 256 rows x 160 cols. XCD-paired decode: halves of the same m share an XCD (A L2 reuse).
// B staged once in LDS (one barrier); K-loop BARRIER-FREE: A 3-deep reg-prefetch from global,
// B-frags 2-deep from LDS. 8 independent waves hide latency.
__global__ __launch_bounds__(512, 2) void egemm_k(
    const u16* __restrict__ A, const u16* __restrict__ Bswz,
    const float* __restrict__ bias, u16* __restrict__ outB)
{
    __shared__ __attribute__((aligned(16))) u16 Bs[160 * 328];
    const int tid = threadIdx.x;
    const int wf = tid >> 6, lane = tid & 63;
    const int wr = wf & 3, wn = wf >> 2;
    const int tl = lane & 15, thi = lane >> 4;
    const int bid = blockIdx.x;
    const long m0 = (long)((bid & 7) + (bid >> 4) * 8) * 256;
    const int half = (bid >> 3) & 1;
    const int n0 = half * 160;
    const int wf_u = __builtin_amdgcn_readfirstlane(wf);
    const u16* Bsrc = Bswz + half * BH_U16;

    #pragma unroll
    for (int i = 0; i < 13; ++i) {
        int t = i * 512 + tid;
        if (t < 6560)
            GLOAD16(Bsrc + (long)t * 8, &Bs[(i * 512 + wf_u * 64) * 8]);
    }

    const u16* gA = A + (m0 + wr * 64 + tl) * 320L + thi * 8;
#define ALD(buf, kb) { _Pragma("unroll") for (int fr = 0; fr < 4; ++fr) \
    buf[fr] = *(const bf16x8*)(gA + fr * (16 * 320L) + (kb) * 32); }

    f32x4 acc[4][5];
    #pragma unroll
    for (int i = 0; i < 4; ++i)
        #pragma unroll
        for (int j = 0; j < 5; ++j) acc[i][j] = (f32x4)(0.f);

    bf16x8 avA[4], avB[4], avC[4], bbA[5], bbB[5];
    ALD(avA, 0); ALD(avB, 1);
    __syncthreads();             // B (and prologue A) ready
    BLD(bbA, 0);

#define CSTEP(KB, AVU, AVP, BBU, BBP) { \
    if ((KB) + 2 < 10) ALD(AVP, (KB) + 2); \
    if ((KB) + 1 < 10) BLD(BBP, (KB) + 1); \
    MMX(AVU, BBU); }

    CSTEP(0, avA, avC, bbA, bbB)
    CSTEP(1, avB, avA, bbB, bbA)
    CSTEP(2, avC, avB, bbA, bbB)
    CSTEP(3, avA, avC, bbB, bbA)
    CSTEP(4, avB, avA, bbA, bbB)
    CSTEP(5, avC, avB, bbB, bbA)
    CSTEP(6, avA, avC, bbA, bbB)
    CSTEP(7, avB, avA, bbB, bbA)
    CSTEP(8, avC, avB, bbA, bbB)
    CSTEP(9, avA, avC, bbB, bbA)
#undef CSTEP
#undef ALD

    #pragma unroll
    for (int fr = 0; fr < 4; ++fr) {
        const long row = m0 + wr * 64 + fr * 16 + tl;
        #pragma unroll
        for (int fc = 0; fc < 5; ++fc) {
            const int c0 = n0 + wn * 80 + fc * 16 + thi * 4;
            f32x4 v = acc[fr][fc];
            if (bias && c0 < 300) {
                const float4 bs = *(const float4*)&bias[c0];
                v[0] += bs.x; v[1] += bs.y; v[2] += bs.z; v[3] += bs.w;
            }
            uint2 p;
            p.x = (u32)f2b(v[0]) | ((u32)f2b(v[1]) << 16);
            p.y = (u32)f2b(v[2]) | ((u32)f2b(v[3]) << 16);
            *(uint2*)&outB[row * 320 + c0] = p;
        }
    }
}

// ---------------- h-update egemm, fused gather A = bf16(fhb[src[e]] - hcur[e^1]) ----------------
// Same barrier-free skeleton; A built in registers (2-deep load pipeline + VALU subtract).
// Epilogue: out = relu(acc + bias + hx[row])  where hx = bf16(x) (read own cell before write).
__global__ __launch_bounds__(512, 2) void egemmmb_k(
    const u16* __restrict__ fhb, const u16* __restrict__ hcur,
    const u16* __restrict__ hx, const int* __restrict__ srcidx,
    const u16* __restrict__ Bswz, const float* __restrict__ bias,
    u16* __restrict__ outB)
{
    __shared__ __attribute__((aligned(16))) u16 Bs[160 * 328];
    const int tid = threadIdx.x;
    const int wf = tid >> 6, lane = tid & 63;
    const int wr = wf & 3, wn = wf >> 2;
    const int tl = lane & 15, thi = lane >> 4;
    const int bid = blockIdx.x;
    const long m0 = (long)((bid & 7) + (bid >> 4) * 8) * 256;
    const int half = (bid >> 3) & 1;
    const int n0 = half * 160;
    const int wf_u = __builtin_amdgcn_readfirstlane(wf);
    const u16* Bsrc = Bswz + half * BH_U16;

    #pragma unroll
    for (int i = 0; i < 13; ++i) {
        int t = i * 512 + tid;
        if (t < 6560)
            GLOAD16(Bsrc + (long)t * 8, &Bs[(i * 512 + wf_u * 64) * 8]);
    }

    const u16* pF[4]; const u16* pH[4];
    #pragma unroll
    for (int fr = 0; fr < 4; ++fr) {
        const long e = m0 + wr * 64 + fr * 16 + tl;
        pF[fr] = fhb + (long)srcidx[e] * 320 + thi * 8;
        pH[fr] = hcur + (e ^ 1) * 320 + thi * 8;
    }

#define MLD(Fs, Hs, kb) { _Pragma("unroll") for (int fr = 0; fr < 4; ++fr) { \
    Fs[fr] = *(const uint4*)(pF[fr] + (kb) * 32); \
    Hs[fr] = *(const uint4*)(pH[fr] + (kb) * 32); } }
#define MAV(av, Fs, Hs) { _Pragma("unroll") for (int fr = 0; fr < 4; ++fr) { \
    uint4 o_; \
    o_.x = bsub2(Fs[fr].x, Hs[fr].x); o_.y = bsub2(Fs[fr].y, Hs[fr].y); \
    o_.z = bsub2(Fs[fr].z, Hs[fr].z); o_.w = bsub2(Fs[fr].w, Hs[fr].w); \
    av[fr] = *(const bf16x8*)&o_; } }

    f32x4 acc[4][5];
    #pragma unroll
    for (int i = 0; i < 4; ++i)
        #pragma unroll
        for (int j = 0; j < 5; ++j) acc[i][j] = (f32x4)(0.f);

    uint4 Fa[4], Ha[4], Fb[4], Hb[4];
    bf16x8 av[4], bbA[5], bbB[5];
    MLD(Fa, Ha, 0); MLD(Fb, Hb, 1);
    __syncthreads();
    BLD(bbA, 0);

#define GSTEP(KB, FU, HU, BBU, BBP) { \
    MAV(av, FU, HU); \
    if ((KB) + 2 < 10) MLD(FU, HU, (KB) + 2); \
    if ((KB) + 1 < 10) BLD(BBP, (KB) + 1); \
    MMX(av, BBU); }

    GSTEP(0, Fa, Ha, bbA, bbB)
    GSTEP(1, Fb, Hb, bbB, bbA)
    GSTEP(2, Fa, Ha, bbA, bbB)
    GSTEP(3, Fb, Hb, bbB, bbA)
    GSTEP(4, Fa, Ha, bbA, bbB)
    GSTEP(5, Fb, Hb, bbB, bbA)
    GSTEP(6, Fa, Ha, bbA, bbB)
    GSTEP(7, Fb, Hb, bbB, bbA)
    GSTEP(8, Fa, Ha, bbA, bbB)
    GSTEP(9, Fb, Hb, bbB, bbA)
#undef GSTEP
#undef MLD
#undef MAV

    #pragma unroll
    for (int fr = 0; fr < 4; ++fr) {
        const long row = m0 + wr * 64 + fr * 16 + tl;
        #pragma unroll
        for (int fc = 0; fc < 5; ++fc) {
            const int c0 = n0 + wn * 80 + fc * 16 + thi * 4;
            f32x4 v = acc[fr][fc];
            if (bias && c0 < 300) {
                const float4 bs = *(const float4*)&bias[c0];
                v[0] += bs.x; v[1] += bs.y; v[2] += bs.z; v[3] += bs.w;
            }
            {
                const ushort4 xv = *(const ushort4*)&hx[row * 320 + c0];
                v[0] += b2f(xv.x); v[1] += b2f(xv.y); v[2] += b2f(xv.z); v[3] += b2f(xv.w);
            }
            v[0] = fmaxf(v[0], 0.f); v[1] = fmaxf(v[1], 0.f);
            v[2] = fmaxf(v[2], 0.f); v[3] = fmaxf(v[3], 0.f);
            uint2 p;
            p.x = (u32)f2b(v[0]) | ((u32)f2b(v[1]) << 16);
            p.y = (u32)f2b(v[2]) | ((u32)f2b(v[3]) << 16);
            *(uint2*)&outB[row * 320 + c0] = p;
        }
    }
}

// ---------------- old-style GEMM kept only for KP=960 final projection ----------------
#define LOADB(bq, kt1) { const long ko_ = (long)(kt1) << 6; \
    _Pragma("unroll") for (int fc = 0; fc < 5; ++fc) \
      _Pragma("unroll") for (int ks = 0; ks < 2; ++ks) \
        bq[fc][ks] = *(const bf16x8*)(gBw + (long)fc * 16 * KP + ko_ + ks * 32); }

#define READA(lkt) { \
    _Pragma("unroll") for (int fr = 0; fr < 4; ++fr) \
      _Pragma("unroll") for (int ks = 0; ks < 2; ++ks) \
        a[fr][ks] = *(const bf16x8*)&As[(fr * 16 + tl) * 320 + ((((lkt) * 8 + ks * 4 + thi) ^ sx) * 8)]; }

#define DOMFMA(bq) { _Pragma("unroll") for (int fr = 0; fr < 4; ++fr) \
    _Pragma("unroll") for (int fc = 0; fc < 5; ++fc) \
      _Pragma("unroll") for (int ks = 0; ks < 2; ++ks) \
        acc[fr][fc] = __builtin_amdgcn_mfma_f32_16x16x32_bf16(bq[fc][ks], a[fr][ks], acc[fr][fc], 0, 0, 0); }

template<int KP>
__global__ __launch_bounds__(256, 2) void gemm_k(
    const u16* __restrict__ A,
    const u16* __restrict__ BT,
    const float* __restrict__ bias,
    float* __restrict__ outF, int ostride, int ocols)
{
    __shared__ u16 As[64 * 320];
    const int tid = threadIdx.x;
    const int w = tid >> 6, lane = tid & 63;
    const int tl = lane & 15, thi = lane >> 4;
    const int sx = tl & 7;
    const long m0 = (long)blockIdx.x * 64;
    const int w_u = __builtin_amdgcn_readfirstlane(w);

    const u16* gBw = BT + ((long)(w * 80 + tl)) * KP + thi * 8;

    f32x4 acc[4][5];
    #pragma unroll
    for (int i = 0; i < 4; ++i)
        #pragma unroll
        for (int j = 0; j < 5; ++j) acc[i][j] = (f32x4)(0.f);

    constexpr int NCH = KP / 320;
    constexpr int NST = KP >> 6;
    bf16x8 bA[5][2], bB[5][2], a[4][2];

    #pragma unroll
    for (int kb = 0; kb < NCH; ++kb) {
        if (kb) __syncthreads();
        #pragma unroll
        for (int i = 0; i < 10; ++i) {
            const int c = i * 256 + w_u * 64 + lane;
            const int r = c / 40, s = c - r * 40;
            GLOAD16(A + (m0 + r) * (long)KP + kb * 320 + ((s ^ (r & 7)) * 8),
                    &As[(i * 256 + w_u * 64) * 8]);
        }
        if (kb == 0) LOADB(bA, 0);
        __syncthreads();
        #pragma unroll
        for (int lkt = 0; lkt < 5; ++lkt) {
            const int kt = kb * 5 + lkt;
            if (kt + 1 < NST) {
                if (kt & 1) { LOADB(bA, kt + 1); } else { LOADB(bB, kt + 1); }
            }
            READA(lkt);
            if (kt & 1) { DOMFMA(bB); } else { DOMFMA(bA); }
        }
    }

    #pragma unroll
    for (int fr = 0; fr < 4; ++fr) {
        const long row = m0 + fr * 16 + tl;
        #pragma unroll
        for (int fc = 0; fc < 5; ++fc) {
            const int c0 = w * 80 + fc * 16 + thi * 4;
            f32x4 v = acc[fr][fc];
            if (bias && c0 < 300) {
                const float4 bs = *(const float4*)&bias[c0];
                v[0] += bs.x; v[1] += bs.y; v[2] += bs.z; v[3] += bs.w;
            }
            if (c0 < ocols)
                *(float4*)&outF[row * (long)ostride + c0] = make_float4(v[0], v[1], v[2], v[3]);
        }
    }
}

// ---------------- fused 8-key 4-head attention, one wave per node (bf16 Q/FV) ----------------
__global__ __launch_bounds__(256) void attn_k(
    const u16* __restrict__ Q, const u16* __restrict__ FV,
    const u16* __restrict__ HK, const u16* __restrict__ HV,
    const int* __restrict__ mail, u16* __restrict__ Ob)
{
    const int tid = threadIdx.x;
    const long n = (long)blockIdx.x * 4 + (tid >> 6);
    const int lane = tid & 63, g = lane >> 4, t = lane & 15;
    const float scale = 0.115470054f;  // 1/sqrt(75)
    const int dbase = g * 75 + t;

    float q[5];
    #pragma unroll
    for (int r = 0; r < 5; ++r)
        q[r] = (t + 16 * r < 75) ? b2f(Q[n * 320 + dbase + 16 * r]) * scale : 0.f;

    int idx[8]; float s[8];
    #pragma unroll
    for (int j = 0; j < 8; ++j) {
        idx[j] = mail[n * 8 + j];
        const u16* kr = HK + (long)idx[j] * 320 + dbase;
        float p = 0.f;
        #pragma unroll
        for (int r = 0; r < 5; ++r) p += q[r] * b2f(kr[16 * r]);
        p += __shfl_xor(p, 8, 64);
        p += __shfl_xor(p, 4, 64);
        p += __shfl_xor(p, 2, 64);
        p += __shfl_xor(p, 1, 64);
        s[j] = p;
    }
    float mx = s[0];
    #pragma unroll
    for (int j = 1; j < 8; ++j) mx = fmaxf(mx, s[j]);
    float sum = 0.f;
    #pragma unroll
    for (int j = 0; j < 8; ++j) { s[j] = __expf(s[j] - mx); sum += s[j]; }
    const float inv = 1.f / sum;

    float o[5];
    #pragma unroll
    for (int r = 0; r < 5; ++r) o[r] = b2f(FV[n * 320 + dbase + 16 * r]);  // softmax sums to 1
    #pragma unroll
    for (int j = 0; j < 8; ++j) {
        const float pj = s[j] * inv;
        const u16* vr = HV + (long)idx[j] * 320 + dbase;
        #pragma unroll
        for (int r = 0; r < 5; ++r) o[r] += pj * b2f(vr[16 * r]);
    }
    #pragma unroll
    for (int r = 0; r < 5; ++r)
        if (t + 16 * r < 75) Ob[n * 320 + dbase + 16 * r] = f2b(o[r]);
    if (lane < 20) Ob[n * 320 + 300 + lane] = 0;   // zero pad cols
}

// ---------------- build concat A = [mail_sum | f_h | f] (bf16, N x 960) ----------------
__global__ __launch_bounds__(256) void concat_k(
    const u16* __restrict__ hb, const u16* __restrict__ fhb,
    const float* __restrict__ f, const int* __restrict__ mail,
    u16* __restrict__ Acat)
{
    const long n = blockIdx.x;
    int m[8];
    #pragma unroll
    for (int j = 0; j < 8; ++j) m[j] = mail[n * 8 + j];
    for (int c = threadIdx.x; c < 960; c += 256) {
        float v;
        if (c < 300) {
            float s = 0.f;
            #pragma unroll
            for (int j = 0; j < 8; ++j) s += b2f(hb[(long)m[j] * 320 + c]);
            v = s;
        } else if (c < 600) v = b2f(fhb[n * 320 + (c - 300)]);
        else if (c < 900) v = f[n * 300 + (c - 600)];
        else v = 0.f;
        Acat[n * 960 + c] = f2b(v);
    }
}

extern "C" void kernel_launch(void* const* d_in, const int* in_sizes, int n_in,
                              void* d_out, int out_size, void* d_ws, size_t ws_size,
                              hipStream_t stream)
{
    const int N = N_NODES, E = E_EDGES;
    const float* f    = (const float*)d_in[0];
    const float* x    = (const float*)d_in[1];
    const int*   mail = (const int*)d_in[2];
    const int*   srcx = (const int*)d_in[3];
    const float* Wq = (const float*)d_in[4];   const float* bq = (const float*)d_in[5];
    const float* Wk = (const float*)d_in[6];   const float* bk = (const float*)d_in[7];
    const float* Wv = (const float*)d_in[8];   const float* bv = (const float*)d_in[9];
    const float* Wo = (const float*)d_in[10];  const float* bo = (const float*)d_in[11];
    const float* Wmp = (const float*)d_in[12]; const float* bmp = (const float*)d_in[13];
    const float* Wlast = (const float*)d_in[14]; const float* blast = (const float*)d_in[15];
    float* out = (float*)d_out;

    char* ws = (char*)d_ws;
    size_t off = 0;
    auto alloc = [&](size_t b) -> void* {
        void* p = ws + off; off += (b + 255) & ~(size_t)255; return p;
    };
    u16* hb   = (u16*)alloc((size_t)E * DP * 2);   // bf16(x); final h after iter 1
    u16* hb2  = (u16*)alloc((size_t)E * DP * 2);   // h after iter 0
    u16* HKb  = (u16*)alloc((size_t)E * DP * 2);   // HK
    u16* HVb  = (u16*)alloc((size_t)E * DP * 2);   // HV; reused as Acat
    u16* Qb   = (u16*)alloc((size_t)N * DP * 2);
    u16* FVb  = (u16*)alloc((size_t)N * DP * 2);
    u16* fhb  = (u16*)alloc((size_t)N * DP * 2);
    u16* Ob   = (u16*)alloc((size_t)N * DP * 2);
    u16* WqS  = (u16*)alloc((size_t)2 * BH_U16 * 2);
    u16* WkS  = (u16*)alloc((size_t)2 * BH_U16 * 2);
    u16* WvS  = (u16*)alloc((size_t)2 * BH_U16 * 2);
    u16* WoS  = (u16*)alloc((size_t)2 * BH_U16 * 2);
    u16* Wm0S = (u16*)alloc((size_t)2 * BH_U16 * 2);
    u16* Wm1S = (u16*)alloc((size_t)2 * BH_U16 * 2);
    u16* WcatB = (u16*)alloc((size_t)KCAT * 320 * 2);

    // ---- weights ----
    {
        int blks = (2 * 160 * 328 + 255) / 256;
        convTswz_k<<<blks, 256, 0, stream>>>(Wq, WqS);
        convTswz_k<<<blks, 256, 0, stream>>>(Wk, WkS);
        convTswz_k<<<blks, 256, 0, stream>>>(Wv, WvS);
        convTswz_k<<<blks, 256, 0, stream>>>(Wo, WoS);
        convTswz_k<<<blks, 256, 0, stream>>>(Wmp, Wm0S);
        convTswz_k<<<blks, 256, 0, stream>>>(Wmp + 90000, Wm1S);
        long totc = (long)320 * KCAT;
        convT_k<<<(int)((totc + 255) / 256), 256, 0, stream>>>(Wlast, 900, 300, WcatB, KCAT, totc);
    }
    // ---- activations: hb = bf16(x), fhb = bf16(f) ----
    {
        long totE = (long)E * (DP / 8);
        padconv_k<<<(int)((totE + 255) / 256), 256, 0, stream>>>(x, 300, hb, DP, totE);
        long totN = (long)N * (DP / 8);
        padconv_k<<<(int)((totN + 255) / 256), 256, 0, stream>>>(f, 300, fhb, DP, totN);
    }

    const int GN = (N / 256) * 2;   // 256
    const int GE = (E / 256) * 2;   // 2048

    for (int it = 0; it < 2; ++it) {
        const u16* WmS = it ? Wm1S : Wm0S;
        const float* bmpi = bmp + it * 300;
        const u16* hcur = it ? hb2 : hb;     // current h
        u16* hnxt = it ? hb : hb2;           // next h (double-buffered; hb also = bf16(x))
        // Q = f_h @ Wq + bq ; FV = f_h @ Wv + bv   (bf16)
        egemm_k<<<GN, 512, 0, stream>>>(fhb, WqS, bq, Qb);
        egemm_k<<<GN, 512, 0, stream>>>(fhb, WvS, bv, FVb);
        // HK = h @ Wk + bk ; HV = h @ Wv            (bf16)
        egemm_k<<<GE, 512, 0, stream>>>(hcur, WkS, bk, HKb);
        egemm_k<<<GE, 512, 0, stream>>>(hcur, WvS, nullptr, HVb);
        // attention -> Ob (bf16)
        attn_k<<<N / 4, 256, 0, stream>>>(Qb, FVb, HKb, HVb, mail, Ob);
        // f_h = O @ Wo + bo (bf16)
        egemm_k<<<GN, 512, 0, stream>>>(Ob, WoS, bo, fhb);
        // h_next = relu(x + (fhb[src] - hcur[e^1]) @ Wmp + bmp)
        egemmmb_k<<<GE, 512, 0, stream>>>(fhb, hcur, hb, srcx, WmS, bmpi, hnxt);
    }

    // Acat = [mail_sum | f_h | f]  (reuse HVb)
    concat_k<<<N, 256, 0, stream>>>(hb, fhb, f, mail, HVb);
    // out = Acat @ Wlast + blast   (f32, stride 300)
    gemm_k<960><<<N / 64, 256, 0, stream>>>(HVb, WcatB, blast, out, 300, 300);
}

// Round 7
// 1824.063 us; speedup vs baseline: 1.0101x; 1.0101x over previous
//
#include <hip/hip_runtime.h>

typedef unsigned short u16;
typedef unsigned int u32;
typedef __bf16 bf16x8 __attribute__((ext_vector_type(8)));
typedef float f32x4 __attribute__((ext_vector_type(4)));

#define N_NODES 32768
#define E_EDGES 262144
#define DP 320          // padded feature dim (300 -> 320)
#define KCAT 960        // padded concat K (900 -> 960)
#define BQ_U16 26240    // one 80-col quarter of padded B: 80*328 u16 (52.5 KB)

__device__ __forceinline__ float b2f(u16 u) {
    union { u32 u; float f; } x; x.u = ((u32)u) << 16; return x.f;
}
__device__ __forceinline__ u16 f2b(float f) {
    union { float f; u32 u; } x; x.f = f;
    u32 r = x.u + 0x7FFF + ((x.u >> 16) & 1);
    return (u16)(r >> 16);
}
__device__ __forceinline__ u32 bsub2(u32 a, u32 b) {
    float lo = b2f((u16)(a & 0xFFFF)) - b2f((u16)(b & 0xFFFF));
    float hi = b2f((u16)(a >> 16))    - b2f((u16)(b >> 16));
    return (u32)f2b(lo) | ((u32)f2b(hi) << 16);
}

#define GLOAD16(g, l) \
    __builtin_amdgcn_global_load_lds((const __attribute__((address_space(1))) u32*)(g), \
                                     (__attribute__((address_space(3))) u32*)(l), 16, 0, 0)

// ---------------- plain weight transpose (final 960-K projection) ----------------
__global__ void convT_k(const float* __restrict__ src, int R, int C,
                        u16* __restrict__ dst, int KP_, long total) {
    long id = (long)blockIdx.x * blockDim.x + threadIdx.x;
    if (id >= total) return;
    int n = (int)(id / KP_), k = (int)(id % KP_);
    dst[id] = (k < R && n < C) ? f2b(src[(long)k * C + n]) : (u16)0;
}

// ---------------- quarter-weight build: dst[q][r][c], c in [0,328) = W[c][q*80+r] ----------------
__global__ void convTq_k(const float* __restrict__ src, u16* __restrict__ dst) {
    int id = blockIdx.x * 256 + threadIdx.x;
    if (id >= 4 * BQ_U16) return;
    int q = id / BQ_U16, rem = id % BQ_U16;
    int r = rem / 328, c = rem % 328;
    int n = q * 80 + r;
    dst[id] = (c < 300 && n < 300) ? f2b(src[(long)c * 300 + n]) : (u16)0;
}

// ---------------- activation pad+convert: f32 MxC -> bf16 MxCP (pad 0) ----------------
__global__ void padconv_k(const float* __restrict__ src, int C,
                          u16* __restrict__ dst, int CP, long total) {
    long id = (long)blockIdx.x * blockDim.x + threadIdx.x;
    if (id >= total) return;
    int cw = CP >> 3;
    long row = id / cw;
    int c8 = (int)(id % cw) * 8;
    u32 w[4];
    #pragma unroll
    for (int p = 0; p < 4; ++p) {
        int c0 = c8 + 2 * p, c1 = c0 + 1;
        u16 lo = (c0 < C) ? f2b(src[row * C + c0]) : (u16)0;
        u16 hi = (c1 < C) ? f2b(src[row * C + c1]) : (u16)0;
        w[p] = (u32)lo | ((u32)hi << 16);
    }
    u32* d = (u32*)(dst + row * CP + c8);
    d[0] = w[0]; d[1] = w[1]; d[2] = w[2]; d[3] = w[3];
}

// ================== egemm tile compute: 128x80 block, 4 waves (32 rows x 80 cols each) ==================
// A LDS: [128][32] u16, slot s of row r holds k-unit s^((r>>1)&3)  (conflict-free b128 reads)
// B LDS: [80][328] u16 padded (conflict-free b128 reads)
// acc[2][5]; mfma swapped-operand: lane -> row=+tl, cols=+thi*4
#define TCOMP(KB, APTR) do { \
    bf16x8 av_[2], bb_[5]; \
    _Pragma("unroll") for (int fr = 0; fr < 2; ++fr) \
        av_[fr] = *(const bf16x8*)&(APTR)[ar0 + fr * 512]; \
    _Pragma("unroll") for (int fc = 0; fc < 5; ++fc) \
        bb_[fc] = *(const bf16x8*)&Bs[br0 + fc * 5248 + (KB) * 32]; \
    __builtin_amdgcn_s_setprio(1); \
    _Pragma("unroll") for (int fr = 0; fr < 2; ++fr) \
        _Pragma("unroll") for (int fc = 0; fc < 5; ++fc) \
            acc[fr][fc] = __builtin_amdgcn_mfma_f32_16x16x32_bf16(bb_[fc], av_[fr], acc[fr][fc], 0, 0, 0); \
    __builtin_amdgcn_s_setprio(0); \
} while (0)

// ---------------- egemm: C(Mx320) = A(Mx320 bf16) @ W (+bias), bf16 out ----------------
// grid = (M/128)*4; XCD-bijective decode groups the 4 col-quarters of one A-tile on one XCD.
// B quarter staged once; A: BK=32, 3-buf LDS pipeline, counted vmcnt(2) + raw s_barrier.
// 77 KB LDS -> 2 blocks/CU: the other block's waves cover this block's barrier stalls.
__global__ __launch_bounds__(256, 2) void egemm_k(
    const u16* __restrict__ A, const u16* __restrict__ Bswz,
    const float* __restrict__ bias, u16* __restrict__ outB)
{
    __shared__ __attribute__((aligned(16))) u16 Bs[80 * 328];
    __shared__ __attribute__((aligned(16))) u16 As3[3][128 * 32];
    const int tid = threadIdx.x;
    const int wf = tid >> 6, lane = tid & 63;
    const int tl = lane & 15, thi = lane >> 4;
    const int bid = blockIdx.x;
    const int gid = (bid & 7) * ((int)gridDim.x >> 3) + (bid >> 3);
    const long m0 = (long)(gid >> 2) * 128;
    const int q = gid & 3;
    const int n0 = q * 80;
    const int wf_u = __builtin_amdgcn_readfirstlane(wf);
    const u16* Bsrc = Bswz + q * BQ_U16;

    // B prologue: 3280 16B chunks (linear src -> linear LDS)
    #pragma unroll
    for (int i = 0; i < 13; ++i) {
        int t = i * 256 + tid;
        if (t < 3280)
            GLOAD16(Bsrc + (long)t * 8, &Bs[(i * 256 + wf_u * 64) * 8]);
    }
    // A staging: task c -> row c>>2, slot c&3; source k-unit g = slot ^ ((row>>1)&3)
    const int r1 = tid >> 2;
    const int g1 = (tid & 3) ^ ((r1 >> 1) & 3);
    const u16* gA0 = A + (m0 + r1) * 320L + g1 * 8;
    const u16* gA1 = A + (m0 + 64 + r1) * 320L + g1 * 8;

#define ESTAGE(KB) { \
    GLOAD16(gA0 + (KB) * 32, &As3[(KB) % 3][wf_u * 512]); \
    GLOAD16(gA1 + (KB) * 32, &As3[(KB) % 3][2048 + wf_u * 512]); }

    ESTAGE(0); ESTAGE(1);

    f32x4 acc[2][5];
    #pragma unroll
    for (int i = 0; i < 2; ++i)
        #pragma unroll
        for (int j = 0; j < 5; ++j) acc[i][j] = (f32x4)(0.f);
    const int ar0 = (wf * 32 + tl) * 32 + (thi ^ ((tl >> 1) & 3)) * 8;
    const int br0 = tl * 328 + thi * 8;

#define ESTEP(KB, VN) { \
    asm volatile("s_waitcnt vmcnt(" #VN ")" ::: "memory"); \
    __builtin_amdgcn_s_barrier(); \
    __builtin_amdgcn_sched_barrier(0); \
    if ((KB) + 2 < 10) ESTAGE((KB) + 2); \
    TCOMP(KB, (&As3[(KB) % 3][0])); }

    ESTEP(0, 2) ESTEP(1, 2) ESTEP(2, 2) ESTEP(3, 2) ESTEP(4, 2)
    ESTEP(5, 2) ESTEP(6, 2) ESTEP(7, 2) ESTEP(8, 2) ESTEP(9, 0)
#undef ESTEP
#undef ESTAGE

    // epilogue: row = m0 + wf*32 + fr*16 + tl ; cols c0.. = n0 + fc*16 + thi*4
    #pragma unroll
    for (int fr = 0; fr < 2; ++fr) {
        const long row = m0 + wf * 32 + fr * 16 + tl;
        #pragma unroll
        for (int fc = 0; fc < 5; ++fc) {
            const int c0 = n0 + fc * 16 + thi * 4;
            f32x4 v = acc[fr][fc];
            if (bias && c0 < 300) {
                const float4 bs = *(const float4*)&bias[c0];
                v[0] += bs.x; v[1] += bs.y; v[2] += bs.z; v[3] += bs.w;
            }
            uint2 p;
            p.x = (u32)f2b(v[0]) | ((u32)f2b(v[1]) << 16);
            p.y = (u32)f2b(v[2]) | ((u32)f2b(v[3]) << 16);
            *(uint2*)&outB[row * 320 + c0] = p;
        }
    }
}

// ---------------- h-update egemm, fused gather A = bf16(fhb[src[e]] - hcur[e^1]) ----------------
// Same skeleton; A reg-staged 2 chunks ahead (2 reg-sets), ds_write after barrier, 2 LDS bufs,
// counted vmcnt(4). Epilogue: out = relu(acc + bias + hx[row]) with hx = bf16(x).
__global__ __launch_bounds__(256, 2) void egemmmb_k(
    const u16* __restrict__ fhb, const u16* __restrict__ hcur,
    const u16* __restrict__ hx, const int* __restrict__ srcidx,
    const u16* __restrict__ Bswz, const float* __restrict__ bias,
    u16* __restrict__ outB)
{
    __shared__ __attribute__((aligned(16))) u16 Bs[80 * 328];
    __shared__ __attribute__((aligned(16))) u16 As2[2][128 * 32];
    const int tid = threadIdx.x;
    const int wf = tid >> 6, lane = tid & 63;
    const int tl = lane & 15, thi = lane >> 4;
    const int bid = blockIdx.x;
    const int gid = (bid & 7) * ((int)gridDim.x >> 3) + (bid >> 3);
    const long m0 = (long)(gid >> 2) * 128;
    const int q = gid & 3;
    const int n0 = q * 80;
    const int wf_u = __builtin_amdgcn_readfirstlane(wf);
    const u16* Bsrc = Bswz + q * BQ_U16;

    #pragma unroll
    for (int i = 0; i < 13; ++i) {
        int t = i * 256 + tid;
        if (t < 3280)
            GLOAD16(Bsrc + (long)t * 8, &Bs[(i * 256 + wf_u * 64) * 8]);
    }
    // gather sources for this thread's two tasks (rows r1, 64+r1, same slot)
    const int r1 = tid >> 2;
    const int g1 = (tid & 3) ^ ((r1 >> 1) & 3);
    const long e0 = m0 + r1, e1 = m0 + 64 + r1;
    const u16* pF0 = fhb + (long)srcidx[e0] * 320 + g1 * 8;
    const u16* pH0 = hcur + (e0 ^ 1) * 320 + g1 * 8;
    const u16* pF1 = fhb + (long)srcidx[e1] * 320 + g1 * 8;
    const u16* pH1 = hcur + (e1 ^ 1) * 320 + g1 * 8;

    uint4 Fa0, Ha0, Fa1, Ha1, Fb0, Hb0, Fb1, Hb1;

#define MLOAD(KB, F0, H0, F1, H1) { \
    F0 = *(const uint4*)(pF0 + (KB) * 32); H0 = *(const uint4*)(pH0 + (KB) * 32); \
    F1 = *(const uint4*)(pF1 + (KB) * 32); H1 = *(const uint4*)(pH1 + (KB) * 32); }

#define MWRITE(KB, F0, H0, F1, H1) { \
    u16* wb_ = &As2[(KB) & 1][0]; \
    uint4 o_; \
    o_.x = bsub2(F0.x, H0.x); o_.y = bsub2(F0.y, H0.y); \
    o_.z = bsub2(F0.z, H0.z); o_.w = bsub2(F0.w, H0.w); \
    *(uint4*)&wb_[tid * 8] = o_; \
    o_.x = bsub2(F1.x, H1.x); o_.y = bsub2(F1.y, H1.y); \
    o_.z = bsub2(F1.z, H1.z); o_.w = bsub2(F1.w, H1.w); \
    *(uint4*)&wb_[(tid + 256) * 8] = o_; }

    MLOAD(0, Fa0, Ha0, Fa1, Ha1);
    MLOAD(1, Fb0, Hb0, Fb1, Hb1);
    asm volatile("s_waitcnt vmcnt(4)" ::: "memory");   // B + chunk0 arrived
    MWRITE(0, Fa0, Ha0, Fa1, Ha1);

    f32x4 acc[2][5];
    #pragma unroll
    for (int i = 0; i < 2; ++i)
        #pragma unroll
        for (int j = 0; j < 5; ++j) acc[i][j] = (f32x4)(0.f);
    const int ar0 = (wf * 32 + tl) * 32 + (thi ^ ((tl >> 1) & 3)) * 8;
    const int br0 = tl * 328 + thi * 8;

#define MSTEP(KB, VN, LF0, LH0, LF1, LH1, SF0, SH0, SF1, SH1) { \
    if ((KB) + 2 < 10) MLOAD((KB) + 2, LF0, LH0, LF1, LH1); \
    asm volatile("s_waitcnt vmcnt(" #VN ")" ::: "memory"); \
    asm volatile("s_waitcnt lgkmcnt(0)" ::: "memory"); \
    __builtin_amdgcn_s_barrier(); \
    __builtin_amdgcn_sched_barrier(0); \
    if ((KB) + 1 < 10) MWRITE((KB) + 1, SF0, SH0, SF1, SH1); \
    TCOMP(KB, (&As2[(KB) & 1][0])); }

    MSTEP(0, 4, Fa0, Ha0, Fa1, Ha1, Fb0, Hb0, Fb1, Hb1)
    MSTEP(1, 4, Fb0, Hb0, Fb1, Hb1, Fa0, Ha0, Fa1, Ha1)
    MSTEP(2, 4, Fa0, Ha0, Fa1, Ha1, Fb0, Hb0, Fb1, Hb1)
    MSTEP(3, 4, Fb0, Hb0, Fb1, Hb1, Fa0, Ha0, Fa1, Ha1)
    MSTEP(4, 4, Fa0, Ha0, Fa1, Ha1, Fb0, Hb0, Fb1, Hb1)
    MSTEP(5, 4, Fb0, Hb0, Fb1, Hb1, Fa0, Ha0, Fa1, Ha1)
    MSTEP(6, 4, Fa0, Ha0, Fa1, Ha1, Fb0, Hb0, Fb1, Hb1)
    MSTEP(7, 4, Fb0, Hb0, Fb1, Hb1, Fa0, Ha0, Fa1, Ha1)
    MSTEP(8, 0, Fa0, Ha0, Fa1, Ha1, Fb0, Hb0, Fb1, Hb1)
    MSTEP(9, 0, Fb0, Hb0, Fb1, Hb1, Fa0, Ha0, Fa1, Ha1)
#undef MSTEP
#undef MLOAD
#undef MWRITE

    #pragma unroll
    for (int fr = 0; fr < 2; ++fr) {
        const long row = m0 + wf * 32 + fr * 16 + tl;
        #pragma unroll
        for (int fc = 0; fc < 5; ++fc) {
            const int c0 = n0 + fc * 16 + thi * 4;
            f32x4 v = acc[fr][fc];
            if (bias && c0 < 300) {
                const float4 bs = *(const float4*)&bias[c0];
                v[0] += bs.x; v[1] += bs.y; v[2] += bs.z; v[3] += bs.w;
            }
            {
                const ushort4 xv = *(const ushort4*)&hx[row * 320 + c0];
                v[0] += b2f(xv.x); v[1] += b2f(xv.y); v[2] += b2f(xv.z); v[3] += b2f(xv.w);
            }
            v[0] = fmaxf(v[0], 0.f); v[1] = fmaxf(v[1], 0.f);
            v[2] = fmaxf(v[2], 0.f); v[3] = fmaxf(v[3], 0.f);
            uint2 p;
            p.x = (u32)f2b(v[0]) | ((u32)f2b(v[1]) << 16);
            p.y = (u32)f2b(v[2]) | ((u32)f2b(v[3]) << 16);
            *(uint2*)&outB[row * 320 + c0] = p;
        }
    }
}

// ---------------- old-style GEMM kept only for KP=960 final projection ----------------
#define LOADB(bq, kt1) { const long ko_ = (long)(kt1) << 6; \
    _Pragma("unroll") for (int fc = 0; fc < 5; ++fc) \
      _Pragma("unroll") for (int ks = 0; ks < 2; ++ks) \
        bq[fc][ks] = *(const bf16x8*)(gBw + (long)fc * 16 * KP + ko_ + ks * 32); }

#define READA(lkt) { \
    _Pragma("unroll") for (int fr = 0; fr < 4; ++fr) \
      _Pragma("unroll") for (int ks = 0; ks < 2; ++ks) \
        a[fr][ks] = *(const bf16x8*)&As[(fr * 16 + tl) * 320 + ((((lkt) * 8 + ks * 4 + thi) ^ sx) * 8)]; }

#define DOMFMA(bq) { _Pragma("unroll") for (int fr = 0; fr < 4; ++fr) \
    _Pragma("unroll") for (int fc = 0; fc < 5; ++fc) \
      _Pragma("unroll") for (int ks = 0; ks < 2; ++ks) \
        acc[fr][fc] = __builtin_amdgcn_mfma_f32_16x16x32_bf16(bq[fc][ks], a[fr][ks], acc[fr][fc], 0, 0, 0); }

template<int KP>
__global__ __launch_bounds__(256, 2) void gemm_k(
    const u16* __restrict__ A,
    const u16* __restrict__ BT,
    const float* __restrict__ bias,
    float* __restrict__ outF, int ostride, int ocols)
{
    __shared__ u16 As[64 * 320];
    const int tid = threadIdx.x;
    const int w = tid >> 6, lane = tid & 63;
    const int tl = lane & 15, thi = lane >> 4;
    const int sx = tl & 7;
    const long m0 = (long)blockIdx.x * 64;
    const int w_u = __builtin_amdgcn_readfirstlane(w);

    const u16* gBw = BT + ((long)(w * 80 + tl)) * KP + thi * 8;

    f32x4 acc[4][5];
    #pragma unroll
    for (int i = 0; i < 4; ++i)
        #pragma unroll
        for (int j = 0; j < 5; ++j) acc[i][j] = (f32x4)(0.f);

    constexpr int NCH = KP / 320;
    constexpr int NST = KP >> 6;
    bf16x8 bA[5][2], bB[5][2], a[4][2];

    #pragma unroll
    for (int kb = 0; kb < NCH; ++kb) {
        if (kb) __syncthreads();
        #pragma unroll
        for (int i = 0; i < 10; ++i) {
            const int c = i * 256 + w_u * 64 + lane;
            const int r = c / 40, s = c - r * 40;
            GLOAD16(A + (m0 + r) * (long)KP + kb * 320 + ((s ^ (r & 7)) * 8),
                    &As[(i * 256 + w_u * 64) * 8]);
        }
        if (kb == 0) LOADB(bA, 0);
        __syncthreads();
        #pragma unroll
        for (int lkt = 0; lkt < 5; ++lkt) {
            const int kt = kb * 5 + lkt;
            if (kt + 1 < NST) {
                if (kt & 1) { LOADB(bA, kt + 1); } else { LOADB(bB, kt + 1); }
            }
            READA(lkt);
            if (kt & 1) { DOMFMA(bB); } else { DOMFMA(bA); }
        }
    }

    #pragma unroll
    for (int fr = 0; fr < 4; ++fr) {
        const long row = m0 + fr * 16 + tl;
        #pragma unroll
        for (int fc = 0; fc < 5; ++fc) {
            const int c0 = w * 80 + fc * 16 + thi * 4;
            f32x4 v = acc[fr][fc];
            if (bias && c0 < 300) {
                const float4 bs = *(const float4*)&bias[c0];
                v[0] += bs.x; v[1] += bs.y; v[2] += bs.z; v[3] += bs.w;
            }
            if (c0 < ocols)
                *(float4*)&outF[row * (long)ostride + c0] = make_float4(v[0], v[1], v[2], v[3]);
        }
    }
}

// ---------------- fused 8-key 4-head attention, one wave per node (bf16 Q/FV) ----------------
__global__ __launch_bounds__(256) void attn_k(
    const u16* __restrict__ Q, const u16* __restrict__ FV,
    const u16* __restrict__ HK, const u16* __restrict__ HV,
    const int* __restrict__ mail, u16* __restrict__ Ob)
{
    const int tid = threadIdx.x;
    const long n = (long)blockIdx.x * 4 + (tid >> 6);
    const int lane = tid & 63, g = lane >> 4, t = lane & 15;
    const float scale = 0.115470054f;  // 1/sqrt(75)
    const int dbase = g * 75 + t;

    float q[5];
    #pragma unroll
    for (int r = 0; r < 5; ++r)
        q[r] = (t + 16 * r < 75) ? b2f(Q[n * 320 + dbase + 16 * r]) * scale : 0.f;

    int idx[8]; float s[8];
    #pragma unroll
    for (int j = 0; j < 8; ++j) {
        idx[j] = mail[n * 8 + j];
        const u16* kr = HK + (long)idx[j] * 320 + dbase;
        float p = 0.f;
        #pragma unroll
        for (int r = 0; r < 5; ++r) p += q[r] * b2f(kr[16 * r]);
        p += __shfl_xor(p, 8, 64);
        p += __shfl_xor(p, 4, 64);
        p += __shfl_xor(p, 2, 64);
        p += __shfl_xor(p, 1, 64);
        s[j] = p;
    }
    float mx = s[0];
    #pragma unroll
    for (int j = 1; j < 8; ++j) mx = fmaxf(mx, s[j]);
    float sum = 0.f;
    #pragma unroll
    for (int j = 0; j < 8; ++j) { s[j] = __expf(s[j] - mx); sum += s[j]; }
    const float inv = 1.f / sum;

    float o[5];
    #pragma unroll
    for (int r = 0; r < 5; ++r) o[r] = b2f(FV[n * 320 + dbase + 16 * r]);  // softmax sums to 1
    #pragma unroll
    for (int j = 0; j < 8; ++j) {
        const float pj = s[j] * inv;
        const u16* vr = HV + (long)idx[j] * 320 + dbase;
        #pragma unroll
        for (int r = 0; r < 5; ++r) o[r] += pj * b2f(vr[16 * r]);
    }
    #pragma unroll
    for (int r = 0; r < 5; ++r)
        if (t + 16 * r < 75) Ob[n * 320 + dbase + 16 * r] = f2b(o[r]);
    if (lane < 20) Ob[n * 320 + 300 + lane] = 0;   // zero pad cols
}

// ---------------- build concat A = [mail_sum | f_h | f] (bf16, N x 960) ----------------
__global__ __launch_bounds__(256) void concat_k(
    const u16* __restrict__ hb, const u16* __restrict__ fhb,
    const float* __restrict__ f, const int* __restrict__ mail,
    u16* __restrict__ Acat)
{
    const long n = blockIdx.x;
    int m[8];
    #pragma unroll
    for (int j = 0; j < 8; ++j) m[j] = mail[n * 8 + j];
    for (int c = threadIdx.x; c < 960; c += 256) {
        float v;
        if (c < 300) {
            float s = 0.f;
            #pragma unroll
            for (int j = 0; j < 8; ++j) s += b2f(hb[(long)m[j] * 320 + c]);
            v = s;
        } else if (c < 600) v = b2f(fhb[n * 320 + (c - 300)]);
        else if (c < 900) v = f[n * 300 + (c - 600)];
        else v = 0.f;
        Acat[n * 960 + c] = f2b(v);
    }
}

extern "C" void kernel_launch(void* const* d_in, const int* in_sizes, int n_in,
                              void* d_out, int out_size, void* d_ws, size_t ws_size,
                              hipStream_t stream)
{
    const int N = N_NODES, E = E_EDGES;
    const float* f    = (const float*)d_in[0];
    const float* x    = (const float*)d_in[1];
    const int*   mail = (const int*)d_in[2];
    const int*   srcx = (const int*)d_in[3];
    const float* Wq = (const float*)d_in[4];   const float* bq = (const float*)d_in[5];
    const float* Wk = (const float*)d_in[6];   const float* bk = (const float*)d_in[7];
    const float* Wv = (const float*)d_in[8];   const float* bv = (const float*)d_in[9];
    const float* Wo = (const float*)d_in[10];  const float* bo = (const float*)d_in[11];
    const float* Wmp = (const float*)d_in[12]; const float* bmp = (const float*)d_in[13];
    const float* Wlast = (const float*)d_in[14]; const float* blast = (const float*)d_in[15];
    float* out = (float*)d_out;

    char* ws = (char*)d_ws;
    size_t off = 0;
    auto alloc = [&](size_t b) -> void* {
        void* p = ws + off; off += (b + 255) & ~(size_t)255; return p;
    };
    u16* hb   = (u16*)alloc((size_t)E * DP * 2);   // bf16(x); final h after iter 1
    u16* hb2  = (u16*)alloc((size_t)E * DP * 2);   // h after iter 0
    u16* HKb  = (u16*)alloc((size_t)E * DP * 2);   // HK
    u16* HVb  = (u16*)alloc((size_t)E * DP * 2);   // HV; reused as Acat
    u16* Qb   = (u16*)alloc((size_t)N * DP * 2);
    u16* FVb  = (u16*)alloc((size_t)N * DP * 2);
    u16* fhb  = (u16*)alloc((size_t)N * DP * 2);
    u16* Ob   = (u16*)alloc((size_t)N * DP * 2);
    u16* WqS  = (u16*)alloc((size_t)4 * BQ_U16 * 2);
    u16* WkS  = (u16*)alloc((size_t)4 * BQ_U16 * 2);
    u16* WvS  = (u16*)alloc((size_t)4 * BQ_U16 * 2);
    u16* WoS  = (u16*)alloc((size_t)4 * BQ_U16 * 2);
    u16* Wm0S = (u16*)alloc((size_t)4 * BQ_U16 * 2);
    u16* Wm1S = (u16*)alloc((size_t)4 * BQ_U16 * 2);
    u16* WcatB = (u16*)alloc((size_t)KCAT * 320 * 2);

    // ---- weights ----
    {
        int blks = (4 * BQ_U16 + 255) / 256;
        convTq_k<<<blks, 256, 0, stream>>>(Wq, WqS);
        convTq_k<<<blks, 256, 0, stream>>>(Wk, WkS);
        convTq_k<<<blks, 256, 0, stream>>>(Wv, WvS);
        convTq_k<<<blks, 256, 0, stream>>>(Wo, WoS);
        convTq_k<<<blks, 256, 0, stream>>>(Wmp, Wm0S);
        convTq_k<<<blks, 256, 0, stream>>>(Wmp + 90000, Wm1S);
        long totc = (long)320 * KCAT;
        convT_k<<<(int)((totc + 255) / 256), 256, 0, stream>>>(Wlast, 900, 300, WcatB, KCAT, totc);
    }
    // ---- activations: hb = bf16(x), fhb = bf16(f) ----
    {
        long totE = (long)E * (DP / 8);
        padconv_k<<<(int)((totE + 255) / 256), 256, 0, stream>>>(x, 300, hb, DP, totE);
        long totN = (long)N * (DP / 8);
        padconv_k<<<(int)((totN + 255) / 256), 256, 0, stream>>>(f, 300, fhb, DP, totN);
    }

    const int GN = (N / 128) * 4;   // 1024 blocks (%8==0)
    const int GE = (E / 128) * 4;   // 8192 blocks (%8==0)

    for (int it = 0; it < 2; ++it) {
        const u16* WmS = it ? Wm1S : Wm0S;
        const float* bmpi = bmp + it * 300;
        const u16* hcur = it ? hb2 : hb;     // current h
        u16* hnxt = it ? hb : hb2;           // next h (double-buffered; hb also = bf16(x))
        // Q = f_h @ Wq + bq ; FV = f_h @ Wv + bv   (bf16)
        egemm_k<<<GN, 256, 0, stream>>>(fhb, WqS, bq, Qb);
        egemm_k<<<GN, 256, 0, stream>>>(fhb, WvS, bv, FVb);
        // HK = h @ Wk + bk ; HV = h @ Wv            (bf16)
        egemm_k<<<GE, 256, 0, stream>>>(hcur, WkS, bk, HKb);
        egemm_k<<<GE, 256, 0, stream>>>(hcur, WvS, nullptr, HVb);
        // attention -> Ob (bf16)
        attn_k<<<N / 4, 256, 0, stream>>>(Qb, FVb, HKb, HVb, mail, Ob);
        // f_h = O @ Wo + bo (bf16)
        egemm_k<<<GN, 256, 0, stream>>>(Ob, WoS, bo, fhb);
        // h_next = relu(x + (fhb[src] - hcur[e^1]) @ Wmp + bmp)
        egemmmb_k<<<GE, 256, 0, stream>>>(fhb, hcur, hb, srcx, WmS, bmpi, hnxt);
    }

    // Acat = [mail_sum | f_h | f]  (reuse HVb)
    concat_k<<<N, 256, 0, stream>>>(hb, fhb, f, mail, HVb);
    // out = Acat @ Wlast + blast   (f32, stride 300)
    gemm_k<960><<<N / 64, 256, 0, stream>>>(HVb, WcatB, blast, out, 300, 300);
}

// Round 8
// 1384.576 us; speedup vs baseline: 1.3307x; 1.3174x over previous
//
#include <hip/hip_runtime.h>

typedef unsigned short u16;
typedef unsigned int u32;
typedef __bf16 bf16x8 __attribute__((ext_vector_type(8)));
typedef float f32x4 __attribute__((ext_vector_type(4)));

#define N_NODES 32768
#define E_EDGES 262144
#define BQ_U16 26240    // one 80-col quarter of padded B: 80*328 u16 (52.5 KB)
#define S75 0.11547005383792515f

__device__ __forceinline__ float b2f(u16 u) {
    union { u32 u; float f; } x; x.u = ((u32)u) << 16; return x.f;
}
__device__ __forceinline__ u16 f2b(float f) {
    union { float f; u32 u; } x; x.f = f;
    u32 r = x.u + 0x7FFF + ((x.u >> 16) & 1);
    return (u16)(r >> 16);
}
__device__ __forceinline__ u32 bsub2(u32 a, u32 b) {
    float lo = b2f((u16)(a & 0xFFFF)) - b2f((u16)(b & 0xFFFF));
    float hi = b2f((u16)(a >> 16))    - b2f((u16)(b >> 16));
    return (u32)f2b(lo) | ((u32)f2b(hi) << 16);
}

#define GLOAD16(g, l) \
    __builtin_amdgcn_global_load_lds((const __attribute__((address_space(1))) u32*)(g), \
                                     (__attribute__((address_space(3))) u32*)(l), 16, 0, 0)

// ---------------- plain weight transpose (final 960-K projection) ----------------
__global__ void convT_k(const float* __restrict__ src, int R, int C,
                        u16* __restrict__ dst, int KP_, long total) {
    long id = (long)blockIdx.x * blockDim.x + threadIdx.x;
    if (id >= total) return;
    int n = (int)(id / KP_), k = (int)(id % KP_);
    dst[id] = (k < R && n < C) ? f2b(src[(long)k * C + n]) : (u16)0;
}

// ---------------- quarter-weight build: dst[q][r][c], c in [0,328) = W[c][q*80+r] ----------------
__global__ void convTq_k(const float* __restrict__ src, u16* __restrict__ dst) {
    int id = blockIdx.x * 256 + threadIdx.x;
    if (id >= 4 * BQ_U16) return;
    int q = id / BQ_U16, rem = id % BQ_U16;
    int r = rem / 328, c = rem % 328;
    int n = q * 80 + r;
    dst[id] = (c < 300 && n < 300) ? f2b(src[(long)c * 300 + n]) : (u16)0;
}

// ---------------- Wqk build (16 quarters of 80 cols, 328-padded K) ----------------
// out col n = 80q+r -> head h=q/4, cc = n-320h. val = S75 * sum_d Wq[c,75h+d]*Wk[cc,75h+d]
__global__ void wqkq_k(const float* __restrict__ Wq, const float* __restrict__ Wk,
                       u16* __restrict__ dst) {
    int id = blockIdx.x * 256 + threadIdx.x;
    if (id >= 16 * BQ_U16) return;
    int q = id / BQ_U16, rem = id % BQ_U16;
    int r = rem / 328, c = rem % 328;
    int h = q >> 2;
    int cc = (q & 3) * 80 + r;
    float acc = 0.f;
    if (c < 300 && cc < 300) {
        const float* wq = Wq + (long)c * 300 + 75 * h;
        const float* wk = Wk + (long)cc * 300 + 75 * h;
        for (int d = 0; d < 75; ++d) acc += wq[d] * wk[d];
        acc *= S75;
    }
    dst[id] = f2b(acc);
}

// bqk[320h+cc] = S75 * sum_d bq[75h+d]*Wk[cc,75h+d]
__global__ void bqk_k(const float* __restrict__ bq, const float* __restrict__ Wk,
                      float* __restrict__ dst) {
    int n = blockIdx.x * 256 + threadIdx.x;
    if (n >= 1280) return;
    int h = n / 320, cc = n % 320;
    float acc = 0.f;
    if (cc < 300) {
        const float* b = bq + 75 * h;
        const float* wk = Wk + (long)cc * 300 + 75 * h;
        for (int d = 0; d < 75; ++d) acc += b[d] * wk[d];
        acc *= S75;
    }
    dst[n] = acc;
}

// ---------------- Ucat build: BT[n][k], n<320 (out col), k<1600, stride 1600 ----------------
// k = 320h+a (k<1280): sum_{d<75} Wv[a,75h+d]*Wo[75h+d,n];  k=1280+a: sum_{d<300} Wv[a,d]*Wo[d,n]
__global__ void ucat_k(const float* __restrict__ Wv, const float* __restrict__ Wo,
                       u16* __restrict__ dst) {
    long id = (long)blockIdx.x * 256 + threadIdx.x;
    if (id >= 320L * 1600) return;
    int n = (int)(id / 1600), k = (int)(id % 1600);
    float acc = 0.f;
    if (n < 300) {
        if (k < 1280) {
            int h = k / 320, a = k % 320;
            if (a < 300) {
                const float* wv = Wv + (long)a * 300 + 75 * h;
                const float* wo = Wo + (long)(75 * h) * 300 + n;
                for (int d = 0; d < 75; ++d) acc += wv[d] * wo[(long)d * 300];
            }
        } else {
            int a = k - 1280;
            if (a < 300) {
                const float* wv = Wv + (long)a * 300;
                const float* wo = Wo + n;
                for (int d = 0; d < 300; ++d) acc += wv[d] * wo[(long)d * 300];
            }
        }
    }
    dst[id] = f2b(acc);
}

// bvo[n] = sum_d bv[d]*Wo[d,n] + bo[n]   (padded to 320, pads 0)
__global__ void bvo_k(const float* __restrict__ bv, const float* __restrict__ Wo,
                      const float* __restrict__ bo, float* __restrict__ dst) {
    int n = blockIdx.x * 256 + threadIdx.x;
    if (n >= 320) return;
    float acc = 0.f;
    if (n < 300) {
        for (int d = 0; d < 300; ++d) acc += bv[d] * Wo[(long)d * 300 + n];
        acc += bo[n];
    }
    dst[n] = acc;
}

// ---------------- activation pad+convert: f32 MxC -> bf16 MxCP (pad 0), optional 2nd dest ----------------
__global__ void padconv_k(const float* __restrict__ src, int C,
                          u16* __restrict__ dst, int CP,
                          u16* __restrict__ dst2, int CP2, long total) {
    long id = (long)blockIdx.x * blockDim.x + threadIdx.x;
    if (id >= total) return;
    int cw = CP >> 3;
    long row = id / cw;
    int c8 = (int)(id % cw) * 8;
    u32 w[4];
    #pragma unroll
    for (int p = 0; p < 4; ++p) {
        int c0 = c8 + 2 * p, c1 = c0 + 1;
        u16 lo = (c0 < C) ? f2b(src[row * C + c0]) : (u16)0;
        u16 hi = (c1 < C) ? f2b(src[row * C + c1]) : (u16)0;
        w[p] = (u32)lo | ((u32)hi << 16);
    }
    u32* d = (u32*)(dst + row * CP + c8);
    d[0] = w[0]; d[1] = w[1]; d[2] = w[2]; d[3] = w[3];
    if (dst2) {
        u32* d2 = (u32*)(dst2 + row * CP2 + c8);
        d2[0] = w[0]; d2[1] = w[1]; d2[2] = w[2]; d2[3] = w[3];
    }
}

// ================== tile compute macro: 128x80 block, 4 waves, acc[2][5] ==================
#define TCOMP(KB, APTR) do { \
    bf16x8 av_[2], bb_[5]; \
    _Pragma("unroll") for (int fr = 0; fr < 2; ++fr) \
        av_[fr] = *(const bf16x8*)&(APTR)[ar0 + fr * 512]; \
    _Pragma("unroll") for (int fc = 0; fc < 5; ++fc) \
        bb_[fc] = *(const bf16x8*)&Bs[br0 + fc * 5248 + (KB) * 32]; \
    __builtin_amdgcn_s_setprio(1); \
    _Pragma("unroll") for (int fr = 0; fr < 2; ++fr) \
        _Pragma("unroll") for (int fc = 0; fc < 5; ++fc) \
            acc[fr][fc] = __builtin_amdgcn_mfma_f32_16x16x32_bf16(bb_[fc], av_[fr], acc[fr][fc], 0, 0, 0); \
    __builtin_amdgcn_s_setprio(0); \
} while (0)

// ---------------- qg GEMM: qg(Nx1280) = fhb(Nx320) @ Wqk (+bqk), bf16 out ----------------
// 128 rows x 80 cols per block; 16 col-quarters; XCD-grouped m-tiles for A L2 reuse.
__global__ __launch_bounds__(256, 2) void qgemm_k(
    const u16* __restrict__ A, const u16* __restrict__ Bswz,
    const float* __restrict__ bias, u16* __restrict__ outB)
{
    __shared__ __attribute__((aligned(16))) u16 Bs[80 * 328];
    __shared__ __attribute__((aligned(16))) u16 As3[3][128 * 32];
    const int tid = threadIdx.x;
    const int wf = tid >> 6, lane = tid & 63;
    const int tl = lane & 15, thi = lane >> 4;
    const int bid = blockIdx.x;
    const int gid = (bid & 7) * ((int)gridDim.x >> 3) + (bid >> 3);
    const long m0 = (long)(gid >> 4) * 128;
    const int q = gid & 15;
    const int n0 = q * 80;
    const int wf_u = __builtin_amdgcn_readfirstlane(wf);
    const u16* Bsrc = Bswz + q * BQ_U16;

    #pragma unroll
    for (int i = 0; i < 13; ++i) {
        int t = i * 256 + tid;
        if (t < 3280)
            GLOAD16(Bsrc + (long)t * 8, &Bs[(i * 256 + wf_u * 64) * 8]);
    }
    const int r1 = tid >> 2;
    const int g1 = (tid & 3) ^ ((r1 >> 1) & 3);
    const u16* gA0 = A + (m0 + r1) * 320L + g1 * 8;
    const u16* gA1 = A + (m0 + 64 + r1) * 320L + g1 * 8;

#define ESTAGE(KB) { \
    GLOAD16(gA0 + (KB) * 32, &As3[(KB) % 3][wf_u * 512]); \
    GLOAD16(gA1 + (KB) * 32, &As3[(KB) % 3][2048 + wf_u * 512]); }

    ESTAGE(0); ESTAGE(1);

    f32x4 acc[2][5];
    #pragma unroll
    for (int i = 0; i < 2; ++i)
        #pragma unroll
        for (int j = 0; j < 5; ++j) acc[i][j] = (f32x4)(0.f);
    const int ar0 = (wf * 32 + tl) * 32 + (thi ^ ((tl >> 1) & 3)) * 8;
    const int br0 = tl * 328 + thi * 8;

#define ESTEP(KB, VN) { \
    asm volatile("s_waitcnt vmcnt(" #VN ")" ::: "memory"); \
    __builtin_amdgcn_s_barrier(); \
    __builtin_amdgcn_sched_barrier(0); \
    if ((KB) + 2 < 10) ESTAGE((KB) + 2); \
    TCOMP(KB, (&As3[(KB) % 3][0])); }

    ESTEP(0, 2) ESTEP(1, 2) ESTEP(2, 2) ESTEP(3, 2) ESTEP(4, 2)
    ESTEP(5, 2) ESTEP(6, 2) ESTEP(7, 2) ESTEP(8, 2) ESTEP(9, 0)
#undef ESTEP
#undef ESTAGE

    #pragma unroll
    for (int fr = 0; fr < 2; ++fr) {
        const long row = m0 + wf * 32 + fr * 16 + tl;
        #pragma unroll
        for (int fc = 0; fc < 5; ++fc) {
            const int c0 = n0 + fc * 16 + thi * 4;
            f32x4 v = acc[fr][fc];
            const float4 bs = *(const float4*)&bias[c0];
            v[0] += bs.x; v[1] += bs.y; v[2] += bs.z; v[3] += bs.w;
            uint2 p;
            p.x = (u32)f2b(v[0]) | ((u32)f2b(v[1]) << 16);
            p.y = (u32)f2b(v[2]) | ((u32)f2b(v[3]) << 16);
            *(uint2*)&outB[row * 1280 + c0] = p;
        }
    }
}

// ---------------- fused attention on raw h: scores qg.h_j, y^h = sum_j p_j h_j ----------------
// one wave per node; lanes 0..39 each own 8 contiguous cols (8*lane..8*lane+7) of the 320-padded rows
__global__ __launch_bounds__(256) void attn2_k(
    const u16* __restrict__ qg, const u16* __restrict__ hcur,
    const int* __restrict__ mail, u16* __restrict__ wideA)
{
    const int tid = threadIdx.x;
    const long n = (long)blockIdx.x * 4 + (tid >> 6);
    const int lane = tid & 63;
    const bool act = lane < 40;
    const int ll = act ? lane : 39;

    int idx[8];
    #pragma unroll
    for (int j = 0; j < 8; ++j) idx[j] = mail[n * 8 + j];
    uint4 hr[8];
    #pragma unroll
    for (int j = 0; j < 8; ++j)
        hr[j] = *(const uint4*)&hcur[(long)idx[j] * 320 + ll * 8];
    uint4 qv[4];
    #pragma unroll
    for (int h = 0; h < 4; ++h)
        qv[h] = *(const uint4*)&qg[n * 1280 + h * 320 + ll * 8];
    if (!act) {
        #pragma unroll
        for (int j = 0; j < 8; ++j) hr[j] = make_uint4(0, 0, 0, 0);
    }

    float qf[4][8];
    #pragma unroll
    for (int h = 0; h < 4; ++h) {
        const u32 w[4] = {qv[h].x, qv[h].y, qv[h].z, qv[h].w};
        #pragma unroll
        for (int p = 0; p < 4; ++p) {
            qf[h][2 * p]     = b2f((u16)(w[p] & 0xFFFF));
            qf[h][2 * p + 1] = b2f((u16)(w[p] >> 16));
        }
    }

    float s[4][8];
    #pragma unroll
    for (int j = 0; j < 8; ++j) {
        float hf[8];
        const u32 w[4] = {hr[j].x, hr[j].y, hr[j].z, hr[j].w};
        #pragma unroll
        for (int p = 0; p < 4; ++p) {
            hf[2 * p]     = b2f((u16)(w[p] & 0xFFFF));
            hf[2 * p + 1] = b2f((u16)(w[p] >> 16));
        }
        #pragma unroll
        for (int h = 0; h < 4; ++h) {
            float d = 0.f;
            #pragma unroll
            for (int m = 0; m < 8; ++m) d += qf[h][m] * hf[m];
            d += __shfl_xor(d, 32, 64);
            d += __shfl_xor(d, 16, 64);
            d += __shfl_xor(d, 8, 64);
            d += __shfl_xor(d, 4, 64);
            d += __shfl_xor(d, 2, 64);
            d += __shfl_xor(d, 1, 64);
            s[h][j] = d;
        }
    }

    float p_[4][8];
    #pragma unroll
    for (int h = 0; h < 4; ++h) {
        float mx = s[h][0];
        #pragma unroll
        for (int j = 1; j < 8; ++j) mx = fmaxf(mx, s[h][j]);
        float sum = 0.f;
        #pragma unroll
        for (int j = 0; j < 8; ++j) { p_[h][j] = __expf(s[h][j] - mx); sum += p_[h][j]; }
        const float inv = 1.f / sum;
        #pragma unroll
        for (int j = 0; j < 8; ++j) p_[h][j] *= inv;
    }

    float y[4][8];
    #pragma unroll
    for (int h = 0; h < 4; ++h)
        #pragma unroll
        for (int m = 0; m < 8; ++m) y[h][m] = 0.f;
    #pragma unroll
    for (int j = 0; j < 8; ++j) {
        float hf[8];
        const u32 w[4] = {hr[j].x, hr[j].y, hr[j].z, hr[j].w};
        #pragma unroll
        for (int p = 0; p < 4; ++p) {
            hf[2 * p]     = b2f((u16)(w[p] & 0xFFFF));
            hf[2 * p + 1] = b2f((u16)(w[p] >> 16));
        }
        #pragma unroll
        for (int h = 0; h < 4; ++h)
            #pragma unroll
            for (int m = 0; m < 8; ++m) y[h][m] += p_[h][j] * hf[m];
    }
    if (act) {
        #pragma unroll
        for (int h = 0; h < 4; ++h) {
            uint4 o;
            o.x = (u32)f2b(y[h][0]) | ((u32)f2b(y[h][1]) << 16);
            o.y = (u32)f2b(y[h][2]) | ((u32)f2b(y[h][3]) << 16);
            o.z = (u32)f2b(y[h][4]) | ((u32)f2b(y[h][5]) << 16);
            o.w = (u32)f2b(y[h][6]) | ((u32)f2b(y[h][7]) << 16);
            *(uint4*)&wideA[n * 1600 + h * 320 + lane * 8] = o;
        }
    }
}

// ---------------- h-update egemm, fused gather A = bf16(fhb[src[e]] - hcur[e^1]) ----------------
// 3-deep register prefetch (covers HBM gather latency), 2 LDS bufs, write-after-barrier.
__global__ __launch_bounds__(256, 2) void egemmmb_k(
    const u16* __restrict__ fhb, const u16* __restrict__ hcur,
    const u16* __restrict__ hx, const int* __restrict__ srcidx,
    const u16* __restrict__ Bswz, const float* __restrict__ bias,
    u16* __restrict__ outB)
{
    __shared__ __attribute__((aligned(16))) u16 Bs[80 * 328];
    __shared__ __attribute__((aligned(16))) u16 As2[2][128 * 32];
    const int tid = threadIdx.x;
    const int wf = tid >> 6, lane = tid & 63;
    const int tl = lane & 15, thi = lane >> 4;
    const int bid = blockIdx.x;
    const int gid = (bid & 7) * ((int)gridDim.x >> 3) + (bid >> 3);
    const long m0 = (long)(gid >> 2) * 128;
    const int q = gid & 3;
    const int n0 = q * 80;
    const int wf_u = __builtin_amdgcn_readfirstlane(wf);
    const u16* Bsrc = Bswz + q * BQ_U16;

    #pragma unroll
    for (int i = 0; i < 13; ++i) {
        int t = i * 256 + tid;
        if (t < 3280)
            GLOAD16(Bsrc + (long)t * 8, &Bs[(i * 256 + wf_u * 64) * 8]);
    }
    const int r1 = tid >> 2;
    const int g1 = (tid & 3) ^ ((r1 >> 1) & 3);
    const long e0 = m0 + r1, e1 = m0 + 64 + r1;
    const u16* pF0 = fhb + (long)srcidx[e0] * 320 + g1 * 8;
    const u16* pH0 = hcur + (e0 ^ 1) * 320 + g1 * 8;
    const u16* pF1 = fhb + (long)srcidx[e1] * 320 + g1 * 8;
    const u16* pH1 = hcur + (e1 ^ 1) * 320 + g1 * 8;

    uint4 Fa0, Ha0, Fa1, Ha1, Fb0, Hb0, Fb1, Hb1, Fc0, Hc0, Fc1, Hc1;

#define MLOAD(KB, F0, H0, F1, H1) { \
    F0 = *(const uint4*)(pF0 + (KB) * 32); H0 = *(const uint4*)(pH0 + (KB) * 32); \
    F1 = *(const uint4*)(pF1 + (KB) * 32); H1 = *(const uint4*)(pH1 + (KB) * 32); }

#define MWRITE(KB, F0, H0, F1, H1) { \
    u16* wb_ = &As2[(KB) & 1][0]; \
    uint4 o_; \
    o_.x = bsub2(F0.x, H0.x); o_.y = bsub2(F0.y, H0.y); \
    o_.z = bsub2(F0.z, H0.z); o_.w = bsub2(F0.w, H0.w); \
    *(uint4*)&wb_[tid * 8] = o_; \
    o_.x = bsub2(F1.x, H1.x); o_.y = bsub2(F1.y, H1.y); \
    o_.z = bsub2(F1.z, H1.z); o_.w = bsub2(F1.w, H1.w); \
    *(uint4*)&wb_[(tid + 256) * 8] = o_; }

    MLOAD(0, Fa0, Ha0, Fa1, Ha1);
    MLOAD(1, Fb0, Hb0, Fb1, Hb1);
    MLOAD(2, Fc0, Hc0, Fc1, Hc1);
    asm volatile("s_waitcnt vmcnt(8)" ::: "memory");   // B + chunk0 done
    MWRITE(0, Fa0, Ha0, Fa1, Ha1);

    f32x4 acc[2][5];
    #pragma unroll
    for (int i = 0; i < 2; ++i)
        #pragma unroll
        for (int j = 0; j < 5; ++j) acc[i][j] = (f32x4)(0.f);
    const int ar0 = (wf * 32 + tl) * 32 + (thi ^ ((tl >> 1) & 3)) * 8;
    const int br0 = tl * 328 + thi * 8;

#define MSTEP(KB, VN, LF0, LH0, LF1, LH1, SF0, SH0, SF1, SH1) { \
    if ((KB) + 3 < 10) MLOAD((KB) + 3, LF0, LH0, LF1, LH1); \
    asm volatile("s_waitcnt vmcnt(" #VN ")" ::: "memory"); \
    asm volatile("s_waitcnt lgkmcnt(0)" ::: "memory"); \
    __builtin_amdgcn_s_barrier(); \
    __builtin_amdgcn_sched_barrier(0); \
    if ((KB) + 1 < 10) MWRITE((KB) + 1, SF0, SH0, SF1, SH1); \
    TCOMP(KB, (&As2[(KB) & 1][0])); }

    // chunk m lives in register-set m%3 (a,b,c)
    MSTEP(0, 8, Fa0, Ha0, Fa1, Ha1, Fb0, Hb0, Fb1, Hb1)   // load3->a, write1(b)
    MSTEP(1, 8, Fb0, Hb0, Fb1, Hb1, Fc0, Hc0, Fc1, Hc1)   // load4->b, write2(c)
    MSTEP(2, 8, Fc0, Hc0, Fc1, Hc1, Fa0, Ha0, Fa1, Ha1)   // load5->c, write3(a)
    MSTEP(3, 8, Fa0, Ha0, Fa1, Ha1, Fb0, Hb0, Fb1, Hb1)   // load6->a, write4(b)
    MSTEP(4, 8, Fb0, Hb0, Fb1, Hb1, Fc0, Hc0, Fc1, Hc1)   // load7->b, write5(c)
    MSTEP(5, 8, Fc0, Hc0, Fc1, Hc1, Fa0, Ha0, Fa1, Ha1)   // load8->c, write6(a)
    MSTEP(6, 8, Fa0, Ha0, Fa1, Ha1, Fb0, Hb0, Fb1, Hb1)   // load9->a, write7(b)
    MSTEP(7, 4, Fb0, Hb0, Fb1, Hb1, Fc0, Hc0, Fc1, Hc1)   //          write8(c)
    MSTEP(8, 0, Fc0, Hc0, Fc1, Hc1, Fa0, Ha0, Fa1, Ha1)   //          write9(a)
    MSTEP(9, 0, Fa0, Ha0, Fa1, Ha1, Fb0, Hb0, Fb1, Hb1)   //          (no write)
#undef MSTEP
#undef MLOAD
#undef MWRITE

    #pragma unroll
    for (int fr = 0; fr < 2; ++fr) {
        const long row = m0 + wf * 32 + fr * 16 + tl;
        #pragma unroll
        for (int fc = 0; fc < 5; ++fc) {
            const int c0 = n0 + fc * 16 + thi * 4;
            f32x4 v = acc[fr][fc];
            if (bias && c0 < 300) {
                const float4 bs = *(const float4*)&bias[c0];
                v[0] += bs.x; v[1] += bs.y; v[2] += bs.z; v[3] += bs.w;
            }
            {
                const ushort4 xv = *(const ushort4*)&hx[row * 320 + c0];
                v[0] += b2f(xv.x); v[1] += b2f(xv.y); v[2] += b2f(xv.z); v[3] += b2f(xv.w);
            }
            v[0] = fmaxf(v[0], 0.f); v[1] = fmaxf(v[1], 0.f);
            v[2] = fmaxf(v[2], 0.f); v[3] = fmaxf(v[3], 0.f);
            uint2 p;
            p.x = (u32)f2b(v[0]) | ((u32)f2b(v[1]) << 16);
            p.y = (u32)f2b(v[2]) | ((u32)f2b(v[3]) << 16);
            *(uint2*)&outB[row * 320 + c0] = p;
        }
    }
}

// ---------------- generic GEMM (64-row tiles, A staged 320-chunks, B from L2 regs) ----------------
#define LOADB(bq, kt1) { const long ko_ = (long)(kt1) << 6; \
    _Pragma("unroll") for (int fc = 0; fc < 5; ++fc) \
      _Pragma("unroll") for (int ks = 0; ks < 2; ++ks) \
        bq[fc][ks] = *(const bf16x8*)(gBw + (long)fc * 16 * KP + ko_ + ks * 32); }

#define READA(lkt) { \
    _Pragma("unroll") for (int fr = 0; fr < 4; ++fr) \
      _Pragma("unroll") for (int ks = 0; ks < 2; ++ks) \
        a[fr][ks] = *(const bf16x8*)&As[(fr * 16 + tl) * 320 + ((((lkt) * 8 + ks * 4 + thi) ^ sx) * 8)]; }

#define DOMFMA(bq) { _Pragma("unroll") for (int fr = 0; fr < 4; ++fr) \
    _Pragma("unroll") for (int fc = 0; fc < 5; ++fc) \
      _Pragma("unroll") for (int ks = 0; ks < 2; ++ks) \
        acc[fr][fc] = __builtin_amdgcn_mfma_f32_16x16x32_bf16(bq[fc][ks], a[fr][ks], acc[fr][fc], 0, 0, 0); }

template<int KP>
__global__ __launch_bounds__(256, 2) void gemm_k(
    const u16* __restrict__ A,
    const u16* __restrict__ BT,
    const float* __restrict__ bias,
    float* __restrict__ outF, int ostride, int ocols,
    u16* __restrict__ outB1, long strideB1,
    u16* __restrict__ outB2, long strideB2)
{
    __shared__ u16 As[64 * 320];
    const int tid = threadIdx.x;
    const int w = tid >> 6, lane = tid & 63;
    const int tl = lane & 15, thi = lane >> 4;
    const int sx = tl & 7;
    const long m0 = (long)blockIdx.x * 64;
    const int w_u = __builtin_amdgcn_readfirstlane(w);

    const u16* gBw = BT + ((long)(w * 80 + tl)) * KP + thi * 8;

    f32x4 acc[4][5];
    #pragma unroll
    for (int i = 0; i < 4; ++i)
        #pragma unroll
        for (int j = 0; j < 5; ++j) acc[i][j] = (f32x4)(0.f);

    constexpr int NCH = KP / 320;
    constexpr int NST = KP >> 6;
    bf16x8 bA[5][2], bB[5][2], a[4][2];

    #pragma unroll
    for (int kb = 0; kb < NCH; ++kb) {
        if (kb) __syncthreads();
        #pragma unroll
        for (int i = 0; i < 10; ++i) {
            const int c = i * 256 + w_u * 64 + lane;
            const int r = c / 40, s = c - r * 40;
            GLOAD16(A + (m0 + r) * (long)KP + kb * 320 + ((s ^ (r & 7)) * 8),
                    &As[(i * 256 + w_u * 64) * 8]);
        }
        if (kb == 0) LOADB(bA, 0);
        __syncthreads();
        #pragma unroll
        for (int lkt = 0; lkt < 5; ++lkt) {
            const int kt = kb * 5 + lkt;
            if (kt + 1 < NST) {
                if (kt & 1) { LOADB(bA, kt + 1); } else { LOADB(bB, kt + 1); }
            }
            READA(lkt);
            if (kt & 1) { DOMFMA(bB); } else { DOMFMA(bA); }
        }
    }

    #pragma unroll
    for (int fr = 0; fr < 4; ++fr) {
        const long row = m0 + fr * 16 + tl;
        #pragma unroll
        for (int fc = 0; fc < 5; ++fc) {
            const int c0 = w * 80 + fc * 16 + thi * 4;
            f32x4 v = acc[fr][fc];
            if (bias && c0 < 300) {
                const float4 bs = *(const float4*)&bias[c0];
                v[0] += bs.x; v[1] += bs.y; v[2] += bs.z; v[3] += bs.w;
            }
            if (outF && c0 < ocols)
                *(float4*)&outF[row * (long)ostride + c0] = make_float4(v[0], v[1], v[2], v[3]);
            if (outB1 || outB2) {
                uint2 p;
                p.x = (u32)f2b(v[0]) | ((u32)f2b(v[1]) << 16);
                p.y = (u32)f2b(v[2]) | ((u32)f2b(v[3]) << 16);
                if (outB1) *(uint2*)&outB1[row * strideB1 + c0] = p;
                if (outB2) *(uint2*)&outB2[row * strideB2 + c0] = p;
            }
        }
    }
}

// ---------------- build concat A = [mail_sum | f_h | f] (bf16, N x 960) ----------------
__global__ __launch_bounds__(256) void concat_k(
    const u16* __restrict__ hb, const u16* __restrict__ fhb,
    const float* __restrict__ f, const int* __restrict__ mail,
    u16* __restrict__ Acat)
{
    const long n = blockIdx.x;
    int m[8];
    #pragma unroll
    for (int j = 0; j < 8; ++j) m[j] = mail[n * 8 + j];
    for (int c = threadIdx.x; c < 960; c += 256) {
        float v;
        if (c < 300) {
            float s = 0.f;
            #pragma unroll
            for (int j = 0; j < 8; ++j) s += b2f(hb[(long)m[j] * 320 + c]);
            v = s;
        } else if (c < 600) v = b2f(fhb[n * 320 + (c - 300)]);
        else if (c < 900) v = f[n * 300 + (c - 600)];
        else v = 0.f;
        Acat[n * 960 + c] = f2b(v);
    }
}

extern "C" void kernel_launch(void* const* d_in, const int* in_sizes, int n_in,
                              void* d_out, int out_size, void* d_ws, size_t ws_size,
                              hipStream_t stream)
{
    const int N = N_NODES, E = E_EDGES;
    const float* f    = (const float*)d_in[0];
    const float* x    = (const float*)d_in[1];
    const int*   mail = (const int*)d_in[2];
    const int*   srcx = (const int*)d_in[3];
    const float* Wq = (const float*)d_in[4];   const float* bq = (const float*)d_in[5];
    const float* Wk = (const float*)d_in[6];   /* bk: softmax-invariant, unused */
    const float* Wv = (const float*)d_in[8];   const float* bv = (const float*)d_in[9];
    const float* Wo = (const float*)d_in[10];  const float* bo = (const float*)d_in[11];
    const float* Wmp = (const float*)d_in[12]; const float* bmp = (const float*)d_in[13];
    const float* Wlast = (const float*)d_in[14]; const float* blast = (const float*)d_in[15];
    float* out = (float*)d_out;

    char* ws = (char*)d_ws;
    size_t off = 0;
    auto alloc = [&](size_t b) -> void* {
        void* p = ws + off; off += (b + 255) & ~(size_t)255; return p;
    };
    u16* hb    = (u16*)alloc((size_t)E * 320 * 2);   // bf16(x); final h after iter 1
    u16* hb2   = (u16*)alloc((size_t)E * 320 * 2);   // h after iter 0
    u16* qgb   = (u16*)alloc((size_t)N * 1280 * 2);  // qg
    u16* wideA = (u16*)alloc((size_t)N * 1600 * 2);  // [Ycat(1280) | feat(320)]
    u16* fhb   = (u16*)alloc((size_t)N * 320 * 2);
    u16* Acat  = (u16*)alloc((size_t)N * 960 * 2);
    u16* WqkS  = (u16*)alloc((size_t)16 * BQ_U16 * 2);
    u16* Wm0S  = (u16*)alloc((size_t)4 * BQ_U16 * 2);
    u16* Wm1S  = (u16*)alloc((size_t)4 * BQ_U16 * 2);
    u16* UcatT = (u16*)alloc((size_t)320 * 1600 * 2);
    u16* WcatB = (u16*)alloc((size_t)960 * 320 * 2);
    float* bqkF = (float*)alloc(1280 * 4);
    float* bvoF = (float*)alloc(320 * 4);

    // ---- weight preprocessing ----
    {
        wqkq_k<<<(16 * BQ_U16 + 255) / 256, 256, 0, stream>>>(Wq, Wk, WqkS);
        bqk_k<<<5, 256, 0, stream>>>(bq, Wk, bqkF);
        ucat_k<<<(int)((320L * 1600 + 255) / 256), 256, 0, stream>>>(Wv, Wo, UcatT);
        bvo_k<<<2, 256, 0, stream>>>(bv, Wo, bo, bvoF);
        int blks = (4 * BQ_U16 + 255) / 256;
        convTq_k<<<blks, 256, 0, stream>>>(Wmp, Wm0S);
        convTq_k<<<blks, 256, 0, stream>>>(Wmp + 90000, Wm1S);
        long totc = (long)320 * 960;
        convT_k<<<(int)((totc + 255) / 256), 256, 0, stream>>>(Wlast, 900, 300, WcatB, 960, totc);
    }
    // ---- activations: hb = bf16(x); fhb = bf16(f) (+ wideA feat slot) ----
    {
        long totE = (long)E * 40;
        padconv_k<<<(int)((totE + 255) / 256), 256, 0, stream>>>(x, 300, hb, 320, nullptr, 0, totE);
        long totN = (long)N * 40;
        padconv_k<<<(int)((totN + 255) / 256), 256, 0, stream>>>(f, 300, fhb, 320, wideA + 1280, 1600, totN);
    }

    const int GQG = (N / 128) * 16;  // 4096 (%8==0)
    const int GE  = (E / 128) * 4;   // 8192 (%8==0)

    for (int it = 0; it < 2; ++it) {
        const u16* WmS = it ? Wm1S : Wm0S;
        const float* bmpi = bmp + it * 300;
        const u16* hcur = it ? hb2 : hb;
        u16* hnxt = it ? hb : hb2;
        // qg = f_h @ Wqk + bqk   (Nx1280 bf16, scale folded)
        qgemm_k<<<GQG, 256, 0, stream>>>(fhb, WqkS, bqkF, qgb);
        // attention on raw h: scores + per-head aggregation -> wideA[:,0:1280]
        attn2_k<<<N / 4, 256, 0, stream>>>(qgb, hcur, mail, wideA);
        // f_h' = [Ycat | feat] @ Ucat + bvo -> fhb AND wideA feat slot (next iter)
        gemm_k<1600><<<N / 64, 256, 0, stream>>>(wideA, UcatT, bvoF,
                                                 nullptr, 0, 0, fhb, 320, wideA + 1280, 1600);
        // h' = relu(x + (f_h'[src] - hcur[e^1]) @ Wmp + bmp)
        egemmmb_k<<<GE, 256, 0, stream>>>(fhb, hcur, hb, srcx, WmS, bmpi, hnxt);
    }

    // Acat = [mail_sum | f_h | f]
    concat_k<<<N, 256, 0, stream>>>(hb, fhb, f, mail, Acat);
    // out = Acat @ Wlast + blast (f32, stride 300)
    gemm_k<960><<<N / 64, 256, 0, stream>>>(Acat, WcatB, blast, out, 300, 300,
                                            nullptr, 0, nullptr, 0);
}

// Round 9
// 1297.068 us; speedup vs baseline: 1.4205x; 1.0675x over previous
//
#include <hip/hip_runtime.h>

typedef unsigned short u16;
typedef unsigned int u32;
typedef __bf16 bf16x8 __attribute__((ext_vector_type(8)));
typedef float f32x4 __attribute__((ext_vector_type(4)));

#define N_NODES 32768
#define E_EDGES 262144
#define BQ_U16 26240    // one 80-col quarter of padded B: 80*328 u16 (52.5 KB)
#define BH_U16 53248    // one 160-col half, padded to 13*512 tasks: 6656*8 u16 (104 KB)
#define S75 0.11547005383792515f

__device__ __forceinline__ float b2f(u16 u) {
    union { u32 u; float f; } x; x.u = ((u32)u) << 16; return x.f;
}
__device__ __forceinline__ u16 f2b(float f) {
    union { float f; u32 u; } x; x.f = f;
    u32 r = x.u + 0x7FFF + ((x.u >> 16) & 1);
    return (u16)(r >> 16);
}
__device__ __forceinline__ u32 bsub2(u32 a, u32 b) {
    float lo = b2f((u16)(a & 0xFFFF)) - b2f((u16)(b & 0xFFFF));
    float hi = b2f((u16)(a >> 16))    - b2f((u16)(b >> 16));
    return (u32)f2b(lo) | ((u32)f2b(hi) << 16);
}

#define GLOAD16(g, l) \
    __builtin_amdgcn_global_load_lds((const __attribute__((address_space(1))) u32*)(g), \
                                     (__attribute__((address_space(3))) u32*)(l), 16, 0, 0)

// ---------------- plain weight transpose (final 960-K projection) ----------------
__global__ void convT_k(const float* __restrict__ src, int R, int C,
                        u16* __restrict__ dst, int KP_, long total) {
    long id = (long)blockIdx.x * blockDim.x + threadIdx.x;
    if (id >= total) return;
    int n = (int)(id / KP_), k = (int)(id % KP_);
    dst[id] = (k < R && n < C) ? f2b(src[(long)k * C + n]) : (u16)0;
}

// ---------------- quarter-weight build: dst[q][r][c], c in [0,328) = W[c][q*80+r] ----------------
__global__ void convTq_k(const float* __restrict__ src, u16* __restrict__ dst) {
    int id = blockIdx.x * 256 + threadIdx.x;
    if (id >= 4 * BQ_U16) return;
    int q = id / BQ_U16, rem = id % BQ_U16;
    int r = rem / 328, c = rem % 328;
    int n = q * 80 + r;
    dst[id] = (c < 300 && n < 300) ? f2b(src[(long)c * 300 + n]) : (u16)0;
}

// ---------------- half-weight build for egemmmb: dst[h][r<160][c<328] + slack zeros ----------------
__global__ void convTh_k(const float* __restrict__ src, u16* __restrict__ dst) {
    int id = blockIdx.x * 256 + threadIdx.x;
    if (id >= 2 * BH_U16) return;
    int h = id / BH_U16, rem = id % BH_U16;
    u16 v = 0;
    if (rem < 160 * 328) {
        int r = rem / 328, c = rem % 328;
        int n = h * 160 + r;
        v = (c < 300 && n < 300) ? f2b(src[(long)c * 300 + n]) : (u16)0;
    }
    dst[id] = v;
}

// ---------------- Wqk build (16 quarters of 80 cols, 328-padded K) ----------------
__global__ void wqkq_k(const float* __restrict__ Wq, const float* __restrict__ Wk,
                       u16* __restrict__ dst) {
    int id = blockIdx.x * 256 + threadIdx.x;
    if (id >= 16 * BQ_U16) return;
    int q = id / BQ_U16, rem = id % BQ_U16;
    int r = rem / 328, c = rem % 328;
    int h = q >> 2;
    int cc = (q & 3) * 80 + r;
    float acc = 0.f;
    if (c < 300 && cc < 300) {
        const float* wq = Wq + (long)c * 300 + 75 * h;
        const float* wk = Wk + (long)cc * 300 + 75 * h;
        for (int d = 0; d < 75; ++d) acc += wq[d] * wk[d];
        acc *= S75;
    }
    dst[id] = f2b(acc);
}

// bqk[320h+cc] = S75 * sum_d bq[75h+d]*Wk[cc,75h+d]
__global__ void bqk_k(const float* __restrict__ bq, const float* __restrict__ Wk,
                      float* __restrict__ dst) {
    int n = blockIdx.x * 256 + threadIdx.x;
    if (n >= 1280) return;
    int h = n / 320, cc = n % 320;
    float acc = 0.f;
    if (cc < 300) {
        const float* b = bq + 75 * h;
        const float* wk = Wk + (long)cc * 300 + 75 * h;
        for (int d = 0; d < 75; ++d) acc += b[d] * wk[d];
        acc *= S75;
    }
    dst[n] = acc;
}

// ---------------- Ucat build: BT[n][k], n<320 (out col), k<1600, stride 1600 ----------------
__global__ void ucat_k(const float* __restrict__ Wv, const float* __restrict__ Wo,
                       u16* __restrict__ dst) {
    long id = (long)blockIdx.x * 256 + threadIdx.x;
    if (id >= 320L * 1600) return;
    int n = (int)(id / 1600), k = (int)(id % 1600);
    float acc = 0.f;
    if (n < 300) {
        if (k < 1280) {
            int h = k / 320, a = k % 320;
            if (a < 300) {
                const float* wv = Wv + (long)a * 300 + 75 * h;
                const float* wo = Wo + (long)(75 * h) * 300 + n;
                for (int d = 0; d < 75; ++d) acc += wv[d] * wo[(long)d * 300];
            }
        } else {
            int a = k - 1280;
            if (a < 300) {
                const float* wv = Wv + (long)a * 300;
                const float* wo = Wo + n;
                for (int d = 0; d < 300; ++d) acc += wv[d] * wo[(long)d * 300];
            }
        }
    }
    dst[id] = f2b(acc);
}

// bvo[n] = sum_d bv[d]*Wo[d,n] + bo[n]
__global__ void bvo_k(const float* __restrict__ bv, const float* __restrict__ Wo,
                      const float* __restrict__ bo, float* __restrict__ dst) {
    int n = blockIdx.x * 256 + threadIdx.x;
    if (n >= 320) return;
    float acc = 0.f;
    if (n < 300) {
        for (int d = 0; d < 300; ++d) acc += bv[d] * Wo[(long)d * 300 + n];
        acc += bo[n];
    }
    dst[n] = acc;
}

// ---------------- activation pad+convert ----------------
__global__ void padconv_k(const float* __restrict__ src, int C,
                          u16* __restrict__ dst, int CP,
                          u16* __restrict__ dst2, int CP2, long total) {
    long id = (long)blockIdx.x * blockDim.x + threadIdx.x;
    if (id >= total) return;
    int cw = CP >> 3;
    long row = id / cw;
    int c8 = (int)(id % cw) * 8;
    u32 w[4];
    #pragma unroll
    for (int p = 0; p < 4; ++p) {
        int c0 = c8 + 2 * p, c1 = c0 + 1;
        u16 lo = (c0 < C) ? f2b(src[row * C + c0]) : (u16)0;
        u16 hi = (c1 < C) ? f2b(src[row * C + c1]) : (u16)0;
        w[p] = (u32)lo | ((u32)hi << 16);
    }
    u32* d = (u32*)(dst + row * CP + c8);
    d[0] = w[0]; d[1] = w[1]; d[2] = w[2]; d[3] = w[3];
    if (dst2) {
        u32* d2 = (u32*)(dst2 + row * CP2 + c8);
        d2[0] = w[0]; d2[1] = w[1]; d2[2] = w[2]; d2[3] = w[3];
    }
}

// ================== tile compute macro (qgemm): 128x80 block, 4 waves, acc[2][5] ==================
#define TCOMP(KB, APTR) do { \
    bf16x8 av_[2], bb_[5]; \
    _Pragma("unroll") for (int fr = 0; fr < 2; ++fr) \
        av_[fr] = *(const bf16x8*)&(APTR)[ar0 + fr * 512]; \
    _Pragma("unroll") for (int fc = 0; fc < 5; ++fc) \
        bb_[fc] = *(const bf16x8*)&Bs[br0 + fc * 5248 + (KB) * 32]; \
    __builtin_amdgcn_s_setprio(1); \
    _Pragma("unroll") for (int fr = 0; fr < 2; ++fr) \
        _Pragma("unroll") for (int fc = 0; fc < 5; ++fc) \
            acc[fr][fc] = __builtin_amdgcn_mfma_f32_16x16x32_bf16(bb_[fc], av_[fr], acc[fr][fc], 0, 0, 0); \
    __builtin_amdgcn_s_setprio(0); \
} while (0)

// ---------------- qg GEMM: qg(Nx1280) = fhb(Nx320) @ Wqk (+bqk), bf16 out ----------------
__global__ __launch_bounds__(256, 2) void qgemm_k(
    const u16* __restrict__ A, const u16* __restrict__ Bswz,
    const float* __restrict__ bias, u16* __restrict__ outB)
{
    __shared__ __attribute__((aligned(16))) u16 Bs[80 * 328];
    __shared__ __attribute__((aligned(16))) u16 As3[3][128 * 32];
    const int tid = threadIdx.x;
    const int wf = tid >> 6, lane = tid & 63;
    const int tl = lane & 15, thi = lane >> 4;
    const int bid = blockIdx.x;
    const int gid = (bid & 7) * ((int)gridDim.x >> 3) + (bid >> 3);
    const long m0 = (long)(gid >> 4) * 128;
    const int q = gid & 15;
    const int n0 = q * 80;
    const int wf_u = __builtin_amdgcn_readfirstlane(wf);
    const u16* Bsrc = Bswz + q * BQ_U16;

    #pragma unroll
    for (int i = 0; i < 13; ++i) {
        int t = i * 256 + tid;
        if (t < 3280)
            GLOAD16(Bsrc + (long)t * 8, &Bs[(i * 256 + wf_u * 64) * 8]);
    }
    const int r1 = tid >> 2;
    const int g1 = (tid & 3) ^ ((r1 >> 1) & 3);
    const u16* gA0 = A + (m0 + r1) * 320L + g1 * 8;
    const u16* gA1 = A + (m0 + 64 + r1) * 320L + g1 * 8;

#define ESTAGE(KB) { \
    GLOAD16(gA0 + (KB) * 32, &As3[(KB) % 3][wf_u * 512]); \
    GLOAD16(gA1 + (KB) * 32, &As3[(KB) % 3][2048 + wf_u * 512]); }

    ESTAGE(0); ESTAGE(1);

    f32x4 acc[2][5];
    #pragma unroll
    for (int i = 0; i < 2; ++i)
        #pragma unroll
        for (int j = 0; j < 5; ++j) acc[i][j] = (f32x4)(0.f);
    const int ar0 = (wf * 32 + tl) * 32 + (thi ^ ((tl >> 1) & 3)) * 8;
    const int br0 = tl * 328 + thi * 8;

#define ESTEP(KB, VN) { \
    asm volatile("s_waitcnt vmcnt(" #VN ")" ::: "memory"); \
    __builtin_amdgcn_s_barrier(); \
    __builtin_amdgcn_sched_barrier(0); \
    if ((KB) + 2 < 10) ESTAGE((KB) + 2); \
    TCOMP(KB, (&As3[(KB) % 3][0])); }

    ESTEP(0, 2) ESTEP(1, 2) ESTEP(2, 2) ESTEP(3, 2) ESTEP(4, 2)
    ESTEP(5, 2) ESTEP(6, 2) ESTEP(7, 2) ESTEP(8, 2) ESTEP(9, 0)
#undef ESTEP
#undef ESTAGE

    #pragma unroll
    for (int fr = 0; fr < 2; ++fr) {
        const long row = m0 + wf * 32 + fr * 16 + tl;
        #pragma unroll
        for (int fc = 0; fc < 5; ++fc) {
            const int c0 = n0 + fc * 16 + thi * 4;
            f32x4 v = acc[fr][fc];
            const float4 bs = *(const float4*)&bias[c0];
            v[0] += bs.x; v[1] += bs.y; v[2] += bs.z; v[3] += bs.w;
            uint2 p;
            p.x = (u32)f2b(v[0]) | ((u32)f2b(v[1]) << 16);
            p.y = (u32)f2b(v[2]) | ((u32)f2b(v[3]) << 16);
            *(uint2*)&outB[row * 1280 + c0] = p;
        }
    }
}

// ---------------- fused attention on raw h ----------------
__global__ __launch_bounds__(256) void attn2_k(
    const u16* __restrict__ qg, const u16* __restrict__ hcur,
    const int* __restrict__ mail, u16* __restrict__ wideA)
{
    const int tid = threadIdx.x;
    const long n = (long)blockIdx.x * 4 + (tid >> 6);
    const int lane = tid & 63;
    const bool act = lane < 40;
    const int ll = act ? lane : 39;

    int idx[8];
    #pragma unroll
    for (int j = 0; j < 8; ++j) idx[j] = mail[n * 8 + j];
    uint4 hr[8];
    #pragma unroll
    for (int j = 0; j < 8; ++j)
        hr[j] = *(const uint4*)&hcur[(long)idx[j] * 320 + ll * 8];
    uint4 qv[4];
    #pragma unroll
    for (int h = 0; h < 4; ++h)
        qv[h] = *(const uint4*)&qg[n * 1280 + h * 320 + ll * 8];
    if (!act) {
        #pragma unroll
        for (int j = 0; j < 8; ++j) hr[j] = make_uint4(0, 0, 0, 0);
    }

    float qf[4][8];
    #pragma unroll
    for (int h = 0; h < 4; ++h) {
        const u32 w[4] = {qv[h].x, qv[h].y, qv[h].z, qv[h].w};
        #pragma unroll
        for (int p = 0; p < 4; ++p) {
            qf[h][2 * p]     = b2f((u16)(w[p] & 0xFFFF));
            qf[h][2 * p + 1] = b2f((u16)(w[p] >> 16));
        }
    }

    float s[4][8];
    #pragma unroll
    for (int j = 0; j < 8; ++j) {
        float hf[8];
        const u32 w[4] = {hr[j].x, hr[j].y, hr[j].z, hr[j].w};
        #pragma unroll
        for (int p = 0; p < 4; ++p) {
            hf[2 * p]     = b2f((u16)(w[p] & 0xFFFF));
            hf[2 * p + 1] = b2f((u16)(w[p] >> 16));
        }
        #pragma unroll
        for (int h = 0; h < 4; ++h) {
            float d = 0.f;
            #pragma unroll
            for (int m = 0; m < 8; ++m) d += qf[h][m] * hf[m];
            d += __shfl_xor(d, 32, 64);
            d += __shfl_xor(d, 16, 64);
            d += __shfl_xor(d, 8, 64);
            d += __shfl_xor(d, 4, 64);
            d += __shfl_xor(d, 2, 64);
            d += __shfl_xor(d, 1, 64);
            s[h][j] = d;
        }
    }

    float p_[4][8];
    #pragma unroll
    for (int h = 0; h < 4; ++h) {
        float mx = s[h][0];
        #pragma unroll
        for (int j = 1; j < 8; ++j) mx = fmaxf(mx, s[h][j]);
        float sum = 0.f;
        #pragma unroll
        for (int j = 0; j < 8; ++j) { p_[h][j] = __expf(s[h][j] - mx); sum += p_[h][j]; }
        const float inv = 1.f / sum;
        #pragma unroll
        for (int j = 0; j < 8; ++j) p_[h][j] *= inv;
    }

    float y[4][8];
    #pragma unroll
    for (int h = 0; h < 4; ++h)
        #pragma unroll
        for (int m = 0; m < 8; ++m) y[h][m] = 0.f;
    #pragma unroll
    for (int j = 0; j < 8; ++j) {
        float hf[8];
        const u32 w[4] = {hr[j].x, hr[j].y, hr[j].z, hr[j].w};
        #pragma unroll
        for (int p = 0; p < 4; ++p) {
            hf[2 * p]     = b2f((u16)(w[p] & 0xFFFF));
            hf[2 * p + 1] = b2f((u16)(w[p] >> 16));
        }
        #pragma unroll
        for (int h = 0; h < 4; ++h)
            #pragma unroll
            for (int m = 0; m < 8; ++m) y[h][m] += p_[h][j] * hf[m];
    }
    if (act) {
        #pragma unroll
        for (int h = 0; h < 4; ++h) {
            uint4 o;
            o.x = (u32)f2b(y[h][0]) | ((u32)f2b(y[h][1]) << 16);
            o.y = (u32)f2b(y[h][2]) | ((u32)f2b(y[h][3]) << 16);
            o.z = (u32)f2b(y[h][4]) | ((u32)f2b(y[h][5]) << 16);
            o.w = (u32)f2b(y[h][6]) | ((u32)f2b(y[h][7]) << 16);
            *(uint4*)&wideA[n * 1600 + h * 320 + lane * 8] = o;
        }
    }
}

// ---------------- h-update egemm: BARRIER-FREE 8-wave, per-wave A staging ----------------
// block = 512 thr (8 waves) x (128 rows x 160 cols). B half [160][328] staged once (1 barrier).
// Each wave owns 16 rows: gathers A = bf16(fhb[src]-hcur[e^1]) into a wave-private 2-buffer
// ([16][72] padded, BK=64), 3 register-sets deep. No K-loop barriers; waves drift freely.
__global__ __launch_bounds__(512, 2) void egemmmb_k(
    const u16* __restrict__ fhb, const u16* __restrict__ hcur,
    const u16* __restrict__ hx, const int* __restrict__ srcidx,
    const u16* __restrict__ Bswz, const float* __restrict__ bias,
    u16* __restrict__ outB)
{
    __shared__ __attribute__((aligned(16))) u16 Bs[BH_U16];      // 104 KB
    __shared__ __attribute__((aligned(16))) u16 As[8 * 2 * 1152]; // 36 KB
    const int tid = threadIdx.x;
    const int wf = tid >> 6, lane = tid & 63;
    const int tl = lane & 15, thi = lane >> 4;
    const int bid = blockIdx.x;
    const int gid = (bid & 7) * ((int)gridDim.x >> 3) + (bid >> 3);
    const long m0 = (long)(gid >> 1) * 128;
    const int n0 = (gid & 1) * 160;
    const int wf_u = __builtin_amdgcn_readfirstlane(wf);
    const u16* Bsrc = Bswz + (gid & 1) * BH_U16;

    // B prologue: 6656 16B tasks, exactly 13 per thread
    #pragma unroll
    for (int i = 0; i < 13; ++i)
        GLOAD16(Bsrc + (long)(i * 512 + tid) * 8, &Bs[(i * 512 + wf_u * 64) * 8]);
    __builtin_amdgcn_sched_barrier(0);

    // gather geometry: lane handles rows rw and rw+8 of its wave tile, col-unit up
    const int rw = lane >> 3;
    const int up = lane & 7;
    const long e0 = m0 + wf * 16 + rw;
    const long e1 = e0 + 8;
    const u16* pF0 = fhb + (long)srcidx[e0] * 320 + up * 8;
    const u16* pH0 = hcur + (e0 ^ 1) * 320 + up * 8;
    const u16* pF1 = fhb + (long)srcidx[e1] * 320 + up * 8;
    const u16* pH1 = hcur + (e1 ^ 1) * 320 + up * 8;
    u16* Aw = &As[wf * 2304];
    const int wi0 = rw * 72 + up * 8;      // write idx row rw
    const int wi1 = wi0 + 576;             // row rw+8

    uint4 Fa0, Ha0, Fa1, Ha1, Fb0, Hb0, Fb1, Hb1, Fc0, Hc0, Fc1, Hc1;

#define MLOADG(KB, F0, H0, F1, H1) { \
    F0 = *(const uint4*)(pF0 + (KB) * 64); H0 = *(const uint4*)(pH0 + (KB) * 64); \
    F1 = *(const uint4*)(pF1 + (KB) * 64); H1 = *(const uint4*)(pH1 + (KB) * 64); }

#define MWRITEG(KB, F0, H0, F1, H1) { \
    u16* wb_ = Aw + ((KB) & 1) * 1152; uint4 o_; \
    o_.x = bsub2(F0.x, H0.x); o_.y = bsub2(F0.y, H0.y); \
    o_.z = bsub2(F0.z, H0.z); o_.w = bsub2(F0.w, H0.w); \
    *(uint4*)&wb_[wi0] = o_; \
    o_.x = bsub2(F1.x, H1.x); o_.y = bsub2(F1.y, H1.y); \
    o_.z = bsub2(F1.z, H1.z); o_.w = bsub2(F1.w, H1.w); \
    *(uint4*)&wb_[wi1] = o_; }

    f32x4 acc[10];
    #pragma unroll
    for (int j = 0; j < 10; ++j) acc[j] = (f32x4)(0.f);

#define GCOMP(KB) { \
    const u16* ab_ = Aw + ((KB) & 1) * 1152; \
    bf16x8 a0_ = *(const bf16x8*)&ab_[tl * 72 + thi * 8]; \
    bf16x8 a1_ = *(const bf16x8*)&ab_[tl * 72 + thi * 8 + 32]; \
    __builtin_amdgcn_s_setprio(1); \
    _Pragma("unroll") for (int fc = 0; fc < 10; ++fc) { \
        const u16* br_ = &Bs[(fc * 16 + tl) * 328 + thi * 8 + (KB) * 64]; \
        bf16x8 b0_ = *(const bf16x8*)&br_[0]; \
        acc[fc] = __builtin_amdgcn_mfma_f32_16x16x32_bf16(b0_, a0_, acc[fc], 0, 0, 0); \
        bf16x8 b1_ = *(const bf16x8*)&br_[32]; \
        acc[fc] = __builtin_amdgcn_mfma_f32_16x16x32_bf16(b1_, a1_, acc[fc], 0, 0, 0); } \
    __builtin_amdgcn_s_setprio(0); }

    MLOADG(0, Fa0, Ha0, Fa1, Ha1);
    MLOADG(1, Fb0, Hb0, Fb1, Hb1);
    __builtin_amdgcn_sched_barrier(0);
    asm volatile("s_waitcnt vmcnt(8)" ::: "memory");   // all 13 B-loads done
    __builtin_amdgcn_s_barrier();
    __builtin_amdgcn_sched_barrier(0);
    MWRITEG(0, Fa0, Ha0, Fa1, Ha1);

    // kb0..4: load(kb+2) ; compute(kb) ; write(kb+1)   — no barriers
    MLOADG(2, Fc0, Hc0, Fc1, Hc1); GCOMP(0); MWRITEG(1, Fb0, Hb0, Fb1, Hb1);
    MLOADG(3, Fa0, Ha0, Fa1, Ha1); GCOMP(1); MWRITEG(2, Fc0, Hc0, Fc1, Hc1);
    MLOADG(4, Fb0, Hb0, Fb1, Hb1); GCOMP(2); MWRITEG(3, Fa0, Ha0, Fa1, Ha1);
    GCOMP(3); MWRITEG(4, Fb0, Hb0, Fb1, Hb1);
    GCOMP(4);
#undef MLOADG
#undef MWRITEG
#undef GCOMP

    // epilogue: row = m0 + wf*16 + tl; cols = n0 + fc*16 + thi*4
    const long row = m0 + wf * 16 + tl;
    #pragma unroll
    for (int fc = 0; fc < 10; ++fc) {
        const int c0 = n0 + fc * 16 + thi * 4;
        f32x4 v = acc[fc];
        if (c0 < 300) {
            const float4 bs = *(const float4*)&bias[c0];
            v[0] += bs.x; v[1] += bs.y; v[2] += bs.z; v[3] += bs.w;
        }
        {
            const ushort4 xv = *(const ushort4*)&hx[row * 320 + c0];
            v[0] += b2f(xv.x); v[1] += b2f(xv.y); v[2] += b2f(xv.z); v[3] += b2f(xv.w);
        }
        v[0] = fmaxf(v[0], 0.f); v[1] = fmaxf(v[1], 0.f);
        v[2] = fmaxf(v[2], 0.f); v[3] = fmaxf(v[3], 0.f);
        uint2 p;
        p.x = (u32)f2b(v[0]) | ((u32)f2b(v[1]) << 16);
        p.y = (u32)f2b(v[2]) | ((u32)f2b(v[3]) << 16);
        *(uint2*)&outB[row * 320 + c0] = p;
    }
}

// ---------------- generic GEMM (64-row tiles) ----------------
#define LOADB(bq, kt1) { const long ko_ = (long)(kt1) << 6; \
    _Pragma("unroll") for (int fc = 0; fc < 5; ++fc) \
      _Pragma("unroll") for (int ks = 0; ks < 2; ++ks) \
        bq[fc][ks] = *(const bf16x8*)(gBw + (long)fc * 16 * KP + ko_ + ks * 32); }

#define READA(lkt) { \
    _Pragma("unroll") for (int fr = 0; fr < 4; ++fr) \
      _Pragma("unroll") for (int ks = 0; ks < 2; ++ks) \
        a[fr][ks] = *(const bf16x8*)&As[(fr * 16 + tl) * 320 + ((((lkt) * 8 + ks * 4 + thi) ^ sx) * 8)]; }

#define DOMFMA(bq) { _Pragma("unroll") for (int fr = 0; fr < 4; ++fr) \
    _Pragma("unroll") for (int fc = 0; fc < 5; ++fc) \
      _Pragma("unroll") for (int ks = 0; ks < 2; ++ks) \
        acc[fr][fc] = __builtin_amdgcn_mfma_f32_16x16x32_bf16(bq[fc][ks], a[fr][ks], acc[fr][fc], 0, 0, 0); }

template<int KP>
__global__ __launch_bounds__(256, 2) void gemm_k(
    const u16* __restrict__ A,
    const u16* __restrict__ BT,
    const float* __restrict__ bias,
    float* __restrict__ outF, int ostride, int ocols,
    u16* __restrict__ outB1, long strideB1,
    u16* __restrict__ outB2, long strideB2)
{
    __shared__ u16 As[64 * 320];
    const int tid = threadIdx.x;
    const int w = tid >> 6, lane = tid & 63;
    const int tl = lane & 15, thi = lane >> 4;
    const int sx = tl & 7;
    const long m0 = (long)blockIdx.x * 64;
    const int w_u = __builtin_amdgcn_readfirstlane(w);

    const u16* gBw = BT + ((long)(w * 80 + tl)) * KP + thi * 8;

    f32x4 acc[4][5];
    #pragma unroll
    for (int i = 0; i < 4; ++i)
        #pragma unroll
        for (int j = 0; j < 5; ++j) acc[i][j] = (f32x4)(0.f);

    constexpr int NCH = KP / 320;
    constexpr int NST = KP >> 6;
    bf16x8 bA[5][2], bB[5][2], a[4][2];

    #pragma unroll
    for (int kb = 0; kb < NCH; ++kb) {
        if (kb) __syncthreads();
        #pragma unroll
        for (int i = 0; i < 10; ++i) {
            const int c = i * 256 + w_u * 64 + lane;
            const int r = c / 40, s = c - r * 40;
            GLOAD16(A + (m0 + r) * (long)KP + kb * 320 + ((s ^ (r & 7)) * 8),
                    &As[(i * 256 + w_u * 64) * 8]);
        }
        if (kb == 0) LOADB(bA, 0);
        __syncthreads();
        #pragma unroll
        for (int lkt = 0; lkt < 5; ++lkt) {
            const int kt = kb * 5 + lkt;
            if (kt + 1 < NST) {
                if (kt & 1) { LOADB(bA, kt + 1); } else { LOADB(bB, kt + 1); }
            }
            READA(lkt);
            if (kt & 1) { DOMFMA(bB); } else { DOMFMA(bA); }
        }
    }

    #pragma unroll
    for (int fr = 0; fr < 4; ++fr) {
        const long row = m0 + fr * 16 + tl;
        #pragma unroll
        for (int fc = 0; fc < 5; ++fc) {
            const int c0 = w * 80 + fc * 16 + thi * 4;
            f32x4 v = acc[fr][fc];
            if (bias && c0 < 300) {
                const float4 bs = *(const float4*)&bias[c0];
                v[0] += bs.x; v[1] += bs.y; v[2] += bs.z; v[3] += bs.w;
            }
            if (outF && c0 < ocols)
                *(float4*)&outF[row * (long)ostride + c0] = make_float4(v[0], v[1], v[2], v[3]);
            if (outB1 || outB2) {
                uint2 p;
                p.x = (u32)f2b(v[0]) | ((u32)f2b(v[1]) << 16);
                p.y = (u32)f2b(v[2]) | ((u32)f2b(v[3]) << 16);
                if (outB1) *(uint2*)&outB1[row * strideB1 + c0] = p;
                if (outB2) *(uint2*)&outB2[row * strideB2 + c0] = p;
            }
        }
    }
}

// ---------------- build concat A = [mail_sum | f_h | f] (bf16, N x 960) ----------------
__global__ __launch_bounds__(256) void concat_k(
    const u16* __restrict__ hb, const u16* __restrict__ fhb,
    const float* __restrict__ f, const int* __restrict__ mail,
    u16* __restrict__ Acat)
{
    const long n = blockIdx.x;
    int m[8];
    #pragma unroll
    for (int j = 0; j < 8; ++j) m[j] = mail[n * 8 + j];
    for (int c = threadIdx.x; c < 960; c += 256) {
        float v;
        if (c < 300) {
            float s = 0.f;
            #pragma unroll
            for (int j = 0; j < 8; ++j) s += b2f(hb[(long)m[j] * 320 + c]);
            v = s;
        } else if (c < 600) v = b2f(fhb[n * 320 + (c - 300)]);
        else if (c < 900) v = f[n * 300 + (c - 600)];
        else v = 0.f;
        Acat[n * 960 + c] = f2b(v);
    }
}

extern "C" void kernel_launch(void* const* d_in, const int* in_sizes, int n_in,
                              void* d_out, int out_size, void* d_ws, size_t ws_size,
                              hipStream_t stream)
{
    const int N = N_NODES, E = E_EDGES;
    const float* f    = (const float*)d_in[0];
    const float* x    = (const float*)d_in[1];
    const int*   mail = (const int*)d_in[2];
    const int*   srcx = (const int*)d_in[3];
    const float* Wq = (const float*)d_in[4];   const float* bq = (const float*)d_in[5];
    const float* Wk = (const float*)d_in[6];   /* bk unused (softmax-invariant) */
    const float* Wv = (const float*)d_in[8];   const float* bv = (const float*)d_in[9];
    const float* Wo = (const float*)d_in[10];  const float* bo = (const float*)d_in[11];
    const float* Wmp = (const float*)d_in[12]; const float* bmp = (const float*)d_in[13];
    const float* Wlast = (const float*)d_in[14]; const float* blast = (const float*)d_in[15];
    float* out = (float*)d_out;

    char* ws = (char*)d_ws;
    size_t off = 0;
    auto alloc = [&](size_t b) -> void* {
        void* p = ws + off; off += (b + 255) & ~(size_t)255; return p;
    };
    u16* hb    = (u16*)alloc((size_t)E * 320 * 2);   // bf16(x); final h after iter 1
    u16* hb2   = (u16*)alloc((size_t)E * 320 * 2);   // h after iter 0
    u16* qgb   = (u16*)alloc((size_t)N * 1280 * 2);  // qg
    u16* wideA = (u16*)alloc((size_t)N * 1600 * 2);  // [Ycat(1280) | feat(320)]
    u16* fhb   = (u16*)alloc((size_t)N * 320 * 2);
    u16* Acat  = (u16*)alloc((size_t)N * 960 * 2);
    u16* WqkS  = (u16*)alloc((size_t)16 * BQ_U16 * 2);
    u16* Wm0S  = (u16*)alloc((size_t)2 * BH_U16 * 2);
    u16* Wm1S  = (u16*)alloc((size_t)2 * BH_U16 * 2);
    u16* UcatT = (u16*)alloc((size_t)320 * 1600 * 2);
    u16* WcatB = (u16*)alloc((size_t)960 * 320 * 2);
    float* bqkF = (float*)alloc(1280 * 4);
    float* bvoF = (float*)alloc(320 * 4);

    // ---- weight preprocessing ----
    {
        wqkq_k<<<(16 * BQ_U16 + 255) / 256, 256, 0, stream>>>(Wq, Wk, WqkS);
        bqk_k<<<5, 256, 0, stream>>>(bq, Wk, bqkF);
        ucat_k<<<(int)((320L * 1600 + 255) / 256), 256, 0, stream>>>(Wv, Wo, UcatT);
        bvo_k<<<2, 256, 0, stream>>>(bv, Wo, bo, bvoF);
        int blksh = (2 * BH_U16 + 255) / 256;
        convTh_k<<<blksh, 256, 0, stream>>>(Wmp, Wm0S);
        convTh_k<<<blksh, 256, 0, stream>>>(Wmp + 90000, Wm1S);
        long totc = (long)320 * 960;
        convT_k<<<(int)((totc + 255) / 256), 256, 0, stream>>>(Wlast, 900, 300, WcatB, 960, totc);
    }
    // ---- activations ----
    {
        long totE = (long)E * 40;
        padconv_k<<<(int)((totE + 255) / 256), 256, 0, stream>>>(x, 300, hb, 320, nullptr, 0, totE);
        long totN = (long)N * 40;
        padconv_k<<<(int)((totN + 255) / 256), 256, 0, stream>>>(f, 300, fhb, 320, wideA + 1280, 1600, totN);
    }

    const int GQG = (N / 128) * 16;  // 4096 (%8==0)
    const int GE2 = (E / 128) * 2;   // 4096 (%8==0)

    for (int it = 0; it < 2; ++it) {
        const u16* WmS = it ? Wm1S : Wm0S;
        const float* bmpi = bmp + it * 300;
        const u16* hcur = it ? hb2 : hb;
        u16* hnxt = it ? hb : hb2;
        // qg = f_h @ Wqk + bqk
        qgemm_k<<<GQG, 256, 0, stream>>>(fhb, WqkS, bqkF, qgb);
        // attention on raw h -> wideA[:,0:1280]
        attn2_k<<<N / 4, 256, 0, stream>>>(qgb, hcur, mail, wideA);
        // f_h' = [Ycat | feat] @ Ucat + bvo
        gemm_k<1600><<<N / 64, 256, 0, stream>>>(wideA, UcatT, bvoF,
                                                 nullptr, 0, 0, fhb, 320, wideA + 1280, 1600);
        // h' = relu(x + (f_h'[src] - hcur[e^1]) @ Wmp + bmp)
        egemmmb_k<<<GE2, 512, 0, stream>>>(fhb, hcur, hb, srcx, WmS, bmpi, hnxt);
    }

    // Acat = [mail_sum | f_h | f]
    concat_k<<<N, 256, 0, stream>>>(hb, fhb, f, mail, Acat);
    // out = Acat @ Wlast + blast
    gemm_k<960><<<N / 64, 256, 0, stream>>>(Acat, WcatB, blast, out, 300, 300,
                                            nullptr, 0, nullptr, 0);
}